// Round 14
// baseline (158.103 us; speedup 1.0000x reference)
//
#include <hip/hip_runtime.h>
#include <stdint.h>

// Problem constants
#define N_ROWS 32768
#define DIM    1024
#define HENC   512
#define NZ     64
#define KE     16
#define HEXP   256
#define NC     10

typedef __attribute__((ext_vector_type(8))) __bf16 bf16x8;
typedef __attribute__((ext_vector_type(4))) float f32x4;
typedef __attribute__((ext_vector_type(8))) unsigned short u16x8;
typedef __attribute__((ext_vector_type(4))) unsigned short u16x4;

__device__ __forceinline__ unsigned short f2bf(float f) {
    __bf16 h = (__bf16)f;  // RNE convert
    return __builtin_bit_cast(unsigned short, h);
}

// async global->LDS, 16B per lane. LDS dst must be wave-uniform (HW adds lane*16).
__device__ __forceinline__ void gload_lds16(void* lds, const void* gsrc) {
    __builtin_amdgcn_global_load_lds(
        (const __attribute__((address_space(1))) unsigned int*)gsrc,
        (__attribute__((address_space(3))) unsigned int*)lds,
        16, 0, 0);
}

// XOR swizzle in bf16-element space: flips 16B-granule bits 3..5 by row&7.
// Applied identically on write (or pre-swizzled global src) and read.
#define SWZ(col, row) ((col) ^ (((row) & 7) << 3))

// ---------------------------------------------------------------------------
// Kernel 0: coalesced cast+transpose via 64x64 LDS tiles (round-10).
// Blocks 0..127: enc_W[1024][512] -> enc_Wt[512][1024]. 128..135: z_W ->
// z_Wt. 136..199: W1[e] -> W1t[e]. 200..215: W2t scalar path (tiny).
// ---------------------------------------------------------------------------
__global__ void prep_weights(const float* __restrict__ enc_W,
                             const float* __restrict__ z_W,
                             const float* __restrict__ W1,
                             const float* __restrict__ W2,
                             unsigned short* __restrict__ enc_Wt,
                             unsigned short* __restrict__ z_Wt,
                             unsigned short* __restrict__ W1t,
                             unsigned short* __restrict__ W2t) {
    const int b = blockIdx.x;
    const int t = threadIdx.x;

    if (b < 200) {
        __shared__ float tile[64][65];
        const float* src;
        unsigned short* dst;
        int R, C, r0, c0;
        if (b < 128) {                         // enc_W [1024][512] -> enc_Wt
            src = enc_W; dst = enc_Wt; R = 1024; C = 512;
            r0 = (b >> 3) * 64; c0 = (b & 7) * 64;
        } else if (b < 136) {                  // z_W [512][64] -> z_Wt
            src = z_W; dst = z_Wt; R = 512; C = 64;
            r0 = (b - 128) * 64; c0 = 0;
        } else {                               // W1[e] [64][256] -> W1t[e]
            int i = b - 136, e = i >> 2, ht = i & 3;
            src = W1 + (size_t)e * (NZ * HEXP);
            dst = W1t + (size_t)e * (HEXP * NZ);
            R = 64; C = 256; r0 = 0; c0 = ht * 64;
        }
        const int rr = t >> 4, cc4 = (t & 15) * 4;
#pragma unroll
        for (int p = 0; p < 4; ++p) {
            float4 v = *(const float4*)(src + (size_t)(r0 + p * 16 + rr) * C + c0 + cc4);
            tile[p * 16 + rr][cc4 + 0] = v.x;
            tile[p * 16 + rr][cc4 + 1] = v.y;
            tile[p * 16 + rr][cc4 + 2] = v.z;
            tile[p * 16 + rr][cc4 + 3] = v.w;
        }
        __syncthreads();
        // Out[c0+orow][r0+cc4+q] = In[r0+cc4+q][c0+orow] = tile[cc4+q][orow]
#pragma unroll
        for (int p = 0; p < 4; ++p) {
            const int orow = p * 16 + rr;
            u16x4 o;
            o[0] = f2bf(tile[cc4 + 0][orow]);
            o[1] = f2bf(tile[cc4 + 1][orow]);
            o[2] = f2bf(tile[cc4 + 2][orow]);
            o[3] = f2bf(tile[cc4 + 3][orow]);
            *(u16x4*)(dst + (size_t)(c0 + orow) * R + r0 + cc4) = o;
        }
    } else {                                   // W2t[e][c][h] = W2[e][h][c], pad
        const int e = b - 200;                 // 0..15
        const int h = t;                       // 0..255
#pragma unroll
        for (int c = 0; c < 16; ++c) {
            W2t[(size_t)(e * 16 + c) * HEXP + h] =
                (c < NC) ? f2bf(W2[((size_t)e * HEXP + h) * NC + c]) : (unsigned short)0;
        }
    }
}

// ---------------------------------------------------------------------------
// Kernel 1 (ROUND-14): FUSED hb-GEMM + z-partial-GEMM, B-from-L2.
// Same BM=128 x BN=256 / BK=64 / 4-wave geometry as the verified best, but
// B is NO LONGER LDS-STAGED: enc_Wt (1 MB, L2-resident) fragments are read
// directly into registers at step top (gemm2/expert-verified pattern). This
// deletes the 8 B-glds whose vmcnt(0) drain dominated barrier1, and halves
// the barrier count to ONE __syncthreads per step. A (X f32) is now
// double-buffered in LDS (2x16 KB; reg-prefetch + cvt + swizzled ds_write to
// the nxt buffer mid-step). Issue order: B-frags FIRST (L2, consumed by the
// MFMAs), A-loads AFTER (newest in the vmcnt FIFO, so B-waits don't force
// them; their counted wait lands in the write phase under MFMA cover).
// LDS = union{As dbuf 32 KB ; hbs 64 KB} = 64 KB -> 2 blocks/CU.
// ---------------------------------------------------------------------------
__launch_bounds__(256, 2)
__global__ void gemm1(const float* __restrict__ X,
                      const unsigned short* __restrict__ Bt,   // enc_Wt [512][1024]
                      const float* __restrict__ enc_b,
                      const unsigned short* __restrict__ zWt,  // [64][512]
                      float* __restrict__ zpart) {             // [2][32768][64]
    __shared__ union G1U {
        unsigned short As[2][128][64];    // 32 KB, double-buffered A
        unsigned short hbs[128][256];     // 64 KB epilogue hb tile
    } u;
    const int t = threadIdx.x;
    const int lane = t & 63;
    const int w = t >> 6;
    const int g = lane >> 4;
    const int l15 = lane & 15;
    const int l7 = l15 & 7;
    const int wm = (w >> 1) * 64;        // wave row base (0/64)
    const int wn = (w & 1) * 128;        // wave col base (0/128)

    // bijective XCD swizzle: nwg=512, 8 XCDs
    const int bid = blockIdx.x;
    const int wgid = (bid & 7) * 64 + (bid >> 3);
    const int m0 = (wgid >> 1) * 128;
    const int n0 = (wgid & 1) * 256;

    // A staging lanes: thread covers rows (t>>4)+16*it, cols (t&15)*4
    const int arow = t >> 4, acolq = t & 15;
    const float* aptr = X + (size_t)(m0 + arow) * DIM + acolq * 4;
    const int ascol = SWZ(acolq * 4, arow);           // swizzled dest col (elems)
    // B fragment base rows for this wave (8 cols x 16 lanes)
    const unsigned short* bfp = Bt + (size_t)(n0 + wn + l15) * DIM + g * 8;

    f32x4 acc[4][8];
#pragma unroll
    for (int i = 0; i < 4; ++i)
#pragma unroll
        for (int j = 0; j < 8; ++j) acc[i][j] = f32x4{0.f, 0.f, 0.f, 0.f};

    // prologue: stage step-0 A into As[0]
    {
        float4 a[8];
#pragma unroll
        for (int it = 0; it < 8; ++it)
            a[it] = *(const float4*)(aptr + (size_t)it * 16 * DIM);
#pragma unroll
        for (int it = 0; it < 8; ++it) {
            u16x4 p;
            p[0] = f2bf(a[it].x); p[1] = f2bf(a[it].y);
            p[2] = f2bf(a[it].z); p[3] = f2bf(a[it].w);
            *(u16x4*)&u.As[0][it * 16 + arow][ascol] = p;
        }
    }
    __syncthreads();

    float4 an[8];
    for (int step = 0; step < 16; ++step) {
        const int cur = step & 1, nxt = cur ^ 1;
        const int k0 = step * 64;

        // 1) B fragments for THIS step, straight from L2 (issued first ->
        //    oldest in vmcnt FIFO; MFMA waits on them don't force A-loads)
        bf16x8 bfr[2][8];
#pragma unroll
        for (int kk = 0; kk < 2; ++kk)
#pragma unroll
            for (int j = 0; j < 8; ++j)
                bfr[kk][j] = *(const bf16x8*)(bfp + (size_t)(j * 16) * DIM + k0 + kk * 32);

        // 2) next-step A loads (newest in FIFO; consumed in phase 4)
        if (step < 15) {
            const int k1 = k0 + 64;
#pragma unroll
            for (int it = 0; it < 8; ++it)
                an[it] = *(const float4*)(aptr + (size_t)it * 16 * DIM + k1);
        }

        // 3) compute: 2 kk halves x (4 row x 8 col) MFMA, A from As[cur]
#pragma unroll
        for (int kk = 0; kk < 2; ++kk) {
            const int sko = SWZ(kk * 32 + g * 8, l7);
            bf16x8 af[4];
#pragma unroll
            for (int i = 0; i < 4; ++i)
                af[i] = *(const bf16x8*)&u.As[cur][wm + i * 16 + l15][sko];
#pragma unroll
            for (int i = 0; i < 4; ++i)
#pragma unroll
                for (int j = 0; j < 8; ++j)
                    acc[i][j] = __builtin_amdgcn_mfma_f32_16x16x32_bf16(af[i], bfr[kk][j], acc[i][j], 0, 0, 0);
        }

        // 4) cvt + write next A into As[nxt] (counted vmcnt wait on an[])
        if (step < 15) {
#pragma unroll
            for (int it = 0; it < 8; ++it) {
                u16x4 p;
                p[0] = f2bf(an[it].x); p[1] = f2bf(an[it].y);
                p[2] = f2bf(an[it].z); p[3] = f2bf(an[it].w);
                *(u16x4*)&u.As[nxt][it * 16 + arow][ascol] = p;
            }
        }
        __syncthreads();   // single barrier/step: As[nxt] ready, As[cur] reads done
    }

    // ---- fused epilogue part 1: relu(acc+bias) -> swizzled bf16 LDS tile ----
#pragma unroll
    for (int j = 0; j < 8; ++j) {
        const int col = wn + j * 16 + l15;            // local col 0..255
        const float bias = enc_b[n0 + col];
#pragma unroll
        for (int i = 0; i < 4; ++i) {
            const int rb = wm + i * 16 + g * 4;
#pragma unroll
            for (int r = 0; r < 4; ++r) {
                float v = acc[i][j][r] + bias;
                v = v > 0.f ? v : 0.f;
                u.hbs[rb + r][SWZ(col, rb + r)] = f2bf(v);
            }
        }
    }
    __syncthreads();

    // ---- fused epilogue part 2: z-partial = hbs @ zWt[:, n0:n0+256] ----
    // wave w: rows w*32..w*32+31 (local), all 64 z-cols, K=256.
    {
        f32x4 zacc[2][4];
#pragma unroll
        for (int i2 = 0; i2 < 2; ++i2)
#pragma unroll
            for (int j2 = 0; j2 < 4; ++j2) zacc[i2][j2] = f32x4{0.f, 0.f, 0.f, 0.f};

        const unsigned short* zwB = zWt + n0;         // k-offset into [64][512]
#pragma unroll
        for (int ks = 0; ks < 8; ++ks) {
            const int k = ks * 32 + g * 8;            // local k 0..255
            bf16x8 bz[4];
#pragma unroll
            for (int j2 = 0; j2 < 4; ++j2)
                bz[j2] = *(const bf16x8*)(zwB + (size_t)(j2 * 16 + l15) * HENC + k);
#pragma unroll
            for (int i2 = 0; i2 < 2; ++i2) {
                const int row = w * 32 + i2 * 16 + l15;
                bf16x8 af = *(const bf16x8*)&u.hbs[row][SWZ(k, row)];
#pragma unroll
                for (int j2 = 0; j2 < 4; ++j2)
                    zacc[i2][j2] = __builtin_amdgcn_mfma_f32_16x16x32_bf16(af, bz[j2], zacc[i2][j2], 0, 0, 0);
            }
        }
        // store partial (f32). C layout: col=l15, row=g*4+r
        float* zp = zpart + (size_t)(n0 ? 1 : 0) * N_ROWS * NZ;
#pragma unroll
        for (int i2 = 0; i2 < 2; ++i2)
#pragma unroll
            for (int j2 = 0; j2 < 4; ++j2) {
                const int colz = j2 * 16 + l15;
#pragma unroll
                for (int r = 0; r < 4; ++r) {
                    const int rowz = m0 + w * 32 + i2 * 16 + g * 4 + r;
                    zp[(size_t)rowz * NZ + colz] = zacc[i2][j2][r];
                }
            }
    }
}

// ---------------------------------------------------------------------------
// Kernel 3 (round-7/10 exact, verified ~33 us): fused q + experts + combine.
// 512 blocks x 64 rows, 4 waves x 16 rows. P0 sums the two z-partials + z_b.
// W1 staged in LDS double-buffered at half-expert granularity via async
// global_load_lds; W2/b1 frags direct from L2 hoisted to expert-top;
// eh per-wave (wave-local LDS, no barrier). Static register indexing only.
// ---------------------------------------------------------------------------
__launch_bounds__(256, 2)
__global__ void expert_kernel(const float* __restrict__ zpart,  // [2][32768][64]
                              const float* __restrict__ z_b,
                              const float* __restrict__ mu,
                              const unsigned short* __restrict__ W1t,  // [16][256][64]
                              const float* __restrict__ b1,
                              const unsigned short* __restrict__ W2t,  // [16][16][256]
                              const float* __restrict__ b2,
                              float* __restrict__ out) {
    __shared__ __align__(16) union SU {
        struct {
            float zs[64][68];    // padded: row stride 68 dwords == 4 mod 32
            float mus[16][68];
            float rn[64];
            float mun[16];
        } a;                                         // ~22.1 KB
        struct {
            unsigned short w1s[2][128][64];          // 32 KB double-buffered W1 halves
            unsigned short ehs[4][16][136];          // per-wave eh, 17.4 KB
        } b;
    } su;
    __shared__ float qs[64][16];                     // 4 KB

    const int t = threadIdx.x;
    const int lane = t & 63;
    const int w = t >> 6;
    const int g = lane >> 4;
    const int l15 = lane & 15;
    const int l7 = l15 & 7;
    const int r0 = blockIdx.x * 64;

    // P0: z = zpart0 + zpart1 + z_b (64x64 f32) + mu into padded LDS
    {
        const float* zp0 = zpart;
        const float* zp1 = zpart + (size_t)N_ROWS * NZ;
#pragma unroll
        for (int it = 0; it < 4; ++it) {
            int idx = it * 256 + t;              // 1024 float4-slots
            int r = idx >> 4, c = (idx & 15) * 4;
            float4 a = *(const float4*)(zp0 + (size_t)(r0 + r) * NZ + c);
            float4 b = *(const float4*)(zp1 + (size_t)(r0 + r) * NZ + c);
            float4 zb = *(const float4*)(z_b + c);
            float4 s;
            s.x = a.x + b.x + zb.x; s.y = a.y + b.y + zb.y;
            s.z = a.z + b.z + zb.z; s.w = a.w + b.w + zb.w;
            *(float4*)&su.a.zs[r][c] = s;
        }
        int r = t >> 4, c = (t & 15) * 4;        // 256 float4-slots for mu
        *(float4*)&su.a.mus[r][c] = *(const float4*)(mu + (size_t)r * NZ + c);
    }
    __syncthreads();

    // P1a: row norms |z|^2 (t<64) and |mu|^2 (t in 64..79)
    if (t < 64) {
        float s = 0.f;
#pragma unroll
        for (int dq = 0; dq < 16; ++dq) {
            float4 v = *(const float4*)&su.a.zs[t][dq * 4];
            s += v.x * v.x + v.y * v.y + v.z * v.z + v.w * v.w;
        }
        su.a.rn[t] = s;
    } else if (t < 80) {
        int k = t - 64;
        float s = 0.f;
#pragma unroll
        for (int dq = 0; dq < 16; ++dq) {
            float4 v = *(const float4*)&su.a.mus[k][dq * 4];
            s += v.x * v.x + v.y * v.y + v.z * v.z + v.w * v.w;
        }
        su.a.mun[k] = s;
    }
    __syncthreads();

    // P1b: z fragments (kept for expert GEMMs) + dist via MFMA -> raw q
    bf16x8 az[2];
#pragma unroll
    for (int ks = 0; ks < 2; ++ks) {
        int row = w * 16 + l15;
        int ko = ks * 32 + g * 8;
        float4 lo = *(const float4*)&su.a.zs[row][ko];
        float4 hi = *(const float4*)&su.a.zs[row][ko + 4];
        u16x8 tmp;
        tmp[0] = f2bf(lo.x); tmp[1] = f2bf(lo.y); tmp[2] = f2bf(lo.z); tmp[3] = f2bf(lo.w);
        tmp[4] = f2bf(hi.x); tmp[5] = f2bf(hi.y); tmp[6] = f2bf(hi.z); tmp[7] = f2bf(hi.w);
        az[ks] = __builtin_bit_cast(bf16x8, tmp);
    }
    {
        bf16x8 bmu[2];
#pragma unroll
        for (int ks = 0; ks < 2; ++ks) {
            int ko = ks * 32 + g * 8;
            float4 lo = *(const float4*)&su.a.mus[l15][ko];
            float4 hi = *(const float4*)&su.a.mus[l15][ko + 4];
            u16x8 tmp;
            tmp[0] = f2bf(lo.x); tmp[1] = f2bf(lo.y); tmp[2] = f2bf(lo.z); tmp[3] = f2bf(lo.w);
            tmp[4] = f2bf(hi.x); tmp[5] = f2bf(hi.y); tmp[6] = f2bf(hi.z); tmp[7] = f2bf(hi.w);
            bmu[ks] = __builtin_bit_cast(bf16x8, tmp);
        }
        f32x4 dacc = f32x4{0.f, 0.f, 0.f, 0.f};
#pragma unroll
        for (int ks = 0; ks < 2; ++ks)
            dacc = __builtin_amdgcn_mfma_f32_16x16x32_bf16(az[ks], bmu[ks], dacc, 0, 0, 0);
#pragma unroll
        for (int r = 0; r < 4; ++r) {
            int rl = w * 16 + g * 4 + r;
            float dist = su.a.rn[rl] - 2.f * dacc[r] + su.a.mun[l15];
            qs[rl][l15] = 1.f / (1.f + dist);
        }
    }
    __syncthreads();

    // P1c: normalize q per row
    if (t < 64) {
        float s = 0.f;
#pragma unroll
        for (int k = 0; k < KE; ++k) s += qs[t][k];
        float inv = 1.f / s;
#pragma unroll
        for (int k = 0; k < KE; ++k) qs[t][k] *= inv;
    }
    __syncthreads();   // qs final, zs dead -> w1s/ehs may alias su.a

    // P3: expert loop with pipelined LDS weight staging.
    const int srow = lane >> 3;                       // 0..7 (row within chunk)
    const int scol = SWZ((lane & 7) * 8, srow);       // pre-swizzled source col

    // prologue: stage half 0 (expert 0, h0) into buf 0
#pragma unroll
    for (int it = 0; it < 4; ++it) {
        const int chunk = it * 4 + w;                 // 16 chunks of 8 rows
        gload_lds16(&su.b.w1s[0][chunk * 8][0],
                    W1t + (size_t)(chunk * 8 + srow) * NZ + scol);
    }
    __syncthreads();                                  // half0 staged

    float pacc[4] = {0.f, 0.f, 0.f, 0.f};
    unsigned short* eh = &su.b.ehs[w][0][0];          // per-wave [16][136]

    for (int e = 0; e < KE; ++e) {
        // expert-top: preload W2 frags + b1 (independent L2 loads, pipelined)
        const unsigned short* w2e = W2t + e * (16 * HEXP);
        bf16x8 w2f[8];
#pragma unroll
        for (int hh = 0; hh < 8; ++hh)
            w2f[hh] = *(const bf16x8*)(w2e + (size_t)l15 * HEXP + hh * 32 + g * 8);
        float b1v[2][8];
#pragma unroll
        for (int half = 0; half < 2; ++half)
#pragma unroll
            for (int j = 0; j < 8; ++j)
                b1v[half][j] = b1[e * HEXP + half * 128 + j * 16 + l15];

        f32x4 la = f32x4{0.f, 0.f, 0.f, 0.f};
#pragma unroll
        for (int half = 0; half < 2; ++half) {
            const int i = e * 2 + half;               // global half index 0..31
            const int cur = i & 1, nxt = cur ^ 1;

            // issue NEXT half's stage first (hidden under this half's MFMAs)
            if (i + 1 < 2 * KE) {
                const int eg = (i + 1) >> 1;
                const int h1 = ((i + 1) & 1) * 128;
                const unsigned short* src =
                    W1t + (size_t)eg * (HEXP * NZ) + (size_t)(h1 + srow) * NZ + scol;
#pragma unroll
                for (int it = 0; it < 4; ++it) {
                    const int chunk = it * 4 + w;
                    gload_lds16(&su.b.w1s[nxt][chunk * 8][0],
                                src + (size_t)chunk * 8 * NZ);
                }
            }

            // eh = relu(z @ W1half + b1) : 16 rows x 128 h, from staged LDS
            f32x4 ea[8];
#pragma unroll
            for (int j = 0; j < 8; ++j) ea[j] = f32x4{0.f, 0.f, 0.f, 0.f};
#pragma unroll
            for (int ks = 0; ks < 2; ++ks) {
                const int sko = SWZ(ks * 32 + g * 8, l7);
#pragma unroll
                for (int j = 0; j < 8; ++j) {
                    bf16x8 bw = *(const bf16x8*)&su.b.w1s[cur][j * 16 + l15][sko];
                    ea[j] = __builtin_amdgcn_mfma_f32_16x16x32_bf16(az[ks], bw, ea[j], 0, 0, 0);
                }
            }
            // bias + relu + bf16 -> per-wave LDS (transpose round-trip)
#pragma unroll
            for (int j = 0; j < 8; ++j) {
#pragma unroll
                for (int r = 0; r < 4; ++r) {
                    float v = ea[j][r] + b1v[half][j];
                    v = v > 0.f ? v : 0.f;
                    eh[(g * 4 + r) * 136 + j * 16 + l15] = f2bf(v);
                }
            }
            // logits partial over this half's 128 h (wave-local read-back)
#pragma unroll
            for (int ks2 = 0; ks2 < 4; ++ks2) {
                bf16x8 ef = *(const bf16x8*)&eh[l15 * 136 + ks2 * 32 + g * 8];
                la = __builtin_amdgcn_mfma_f32_16x16x32_bf16(ef, w2f[half * 4 + ks2], la, 0, 0, 0);
            }
            __syncthreads();   // drains next-half stage; WAR-protects buffers
        }

        // combine: preds += q[:,e] * (logits + b2[e])
        float b2v = (l15 < NC) ? b2[e * NC + l15] : 0.f;
#pragma unroll
        for (int r = 0; r < 4; ++r) {
            int rl = w * 16 + g * 4 + r;
            pacc[r] += qs[rl][e] * (la[r] + b2v);
        }
    }

    // P4: store preds
    if (l15 < NC) {
#pragma unroll
        for (int r = 0; r < 4; ++r) {
            int row = r0 + w * 16 + g * 4 + r;
            out[(size_t)row * NC + l15] = pacc[r];
        }
    }
}

// ---------------------------------------------------------------------------
extern "C" void kernel_launch(void* const* d_in, const int* in_sizes, int n_in,
                              void* d_out, int out_size, void* d_ws, size_t ws_size,
                              hipStream_t stream) {
    const float* X     = (const float*)d_in[0];
    const float* enc_W = (const float*)d_in[1];
    const float* enc_b = (const float*)d_in[2];
    const float* z_W   = (const float*)d_in[3];
    const float* z_b   = (const float*)d_in[4];
    const float* mu    = (const float*)d_in[5];
    const float* W1    = (const float*)d_in[6];
    const float* b1    = (const float*)d_in[7];
    const float* W2    = (const float*)d_in[8];
    const float* b2    = (const float*)d_in[9];
    float* out = (float*)d_out;

    // workspace layout (~18.5 MB)
    char* ws = (char*)d_ws;
    float*          zpart  = (float*)(ws);                       // 16,777,216 B
    unsigned short* enc_Wt = (unsigned short*)(ws + 16777216);   //  1,048,576 B
    unsigned short* z_Wt   = (unsigned short*)(ws + 17825792);   //     65,536 B
    unsigned short* W1t    = (unsigned short*)(ws + 17891328);   //    524,288 B
    unsigned short* W2t    = (unsigned short*)(ws + 18415616);   //    131,072 B

    prep_weights<<<dim3(216), dim3(256), 0, stream>>>(enc_W, z_W, W1, W2,
                                                      enc_Wt, z_Wt, W1t, W2t);
    gemm1<<<dim3(512), dim3(256), 0, stream>>>(X, enc_Wt, enc_b, z_Wt, zpart);
    expert_kernel<<<dim3(512), dim3(256), 0, stream>>>(zpart, z_b, mu, W1t, b1, W2t, b2, out);
}

// Round 15
// 121.230 us; speedup vs baseline: 1.3042x; 1.3042x over previous
//
#include <hip/hip_runtime.h>
#include <stdint.h>

// Problem constants
#define N_ROWS 32768
#define DIM    1024
#define HENC   512
#define NZ     64
#define KE     16
#define HEXP   256
#define NC     10

typedef __attribute__((ext_vector_type(8))) __bf16 bf16x8;
typedef __attribute__((ext_vector_type(4))) float f32x4;
typedef __attribute__((ext_vector_type(8))) unsigned short u16x8;
typedef __attribute__((ext_vector_type(4))) unsigned short u16x4;

__device__ __forceinline__ unsigned short f2bf(float f) {
    __bf16 h = (__bf16)f;  // RNE convert
    return __builtin_bit_cast(unsigned short, h);
}

// async global->LDS, 16B per lane. LDS dst must be wave-uniform (HW adds lane*16).
__device__ __forceinline__ void gload_lds16(void* lds, const void* gsrc) {
    __builtin_amdgcn_global_load_lds(
        (const __attribute__((address_space(1))) unsigned int*)gsrc,
        (__attribute__((address_space(3))) unsigned int*)lds,
        16, 0, 0);
}

// XOR swizzle in bf16-element space: flips 16B-granule bits 3..5 by row&7.
// Applied identically on write (or pre-swizzled global src) and read.
#define SWZ(col, row) ((col) ^ (((row) & 7) << 3))

// ---------------------------------------------------------------------------
// Kernel 0: coalesced cast+transpose via 64x64 LDS tiles (round-10).
// Blocks 0..127: enc_W[1024][512] -> enc_Wt[512][1024]. 128..135: z_W ->
// z_Wt. 136..199: W1[e] -> W1t[e]. 200..215: W2t scalar path (tiny).
// ---------------------------------------------------------------------------
__global__ void prep_weights(const float* __restrict__ enc_W,
                             const float* __restrict__ z_W,
                             const float* __restrict__ W1,
                             const float* __restrict__ W2,
                             unsigned short* __restrict__ enc_Wt,
                             unsigned short* __restrict__ z_Wt,
                             unsigned short* __restrict__ W1t,
                             unsigned short* __restrict__ W2t) {
    const int b = blockIdx.x;
    const int t = threadIdx.x;

    if (b < 200) {
        __shared__ float tile[64][65];
        const float* src;
        unsigned short* dst;
        int R, C, r0, c0;
        if (b < 128) {                         // enc_W [1024][512] -> enc_Wt
            src = enc_W; dst = enc_Wt; R = 1024; C = 512;
            r0 = (b >> 3) * 64; c0 = (b & 7) * 64;
        } else if (b < 136) {                  // z_W [512][64] -> z_Wt
            src = z_W; dst = z_Wt; R = 512; C = 64;
            r0 = (b - 128) * 64; c0 = 0;
        } else {                               // W1[e] [64][256] -> W1t[e]
            int i = b - 136, e = i >> 2, ht = i & 3;
            src = W1 + (size_t)e * (NZ * HEXP);
            dst = W1t + (size_t)e * (HEXP * NZ);
            R = 64; C = 256; r0 = 0; c0 = ht * 64;
        }
        const int rr = t >> 4, cc4 = (t & 15) * 4;
#pragma unroll
        for (int p = 0; p < 4; ++p) {
            float4 v = *(const float4*)(src + (size_t)(r0 + p * 16 + rr) * C + c0 + cc4);
            tile[p * 16 + rr][cc4 + 0] = v.x;
            tile[p * 16 + rr][cc4 + 1] = v.y;
            tile[p * 16 + rr][cc4 + 2] = v.z;
            tile[p * 16 + rr][cc4 + 3] = v.w;
        }
        __syncthreads();
        // Out[c0+orow][r0+cc4+q] = In[r0+cc4+q][c0+orow] = tile[cc4+q][orow]
#pragma unroll
        for (int p = 0; p < 4; ++p) {
            const int orow = p * 16 + rr;
            u16x4 o;
            o[0] = f2bf(tile[cc4 + 0][orow]);
            o[1] = f2bf(tile[cc4 + 1][orow]);
            o[2] = f2bf(tile[cc4 + 2][orow]);
            o[3] = f2bf(tile[cc4 + 3][orow]);
            *(u16x4*)(dst + (size_t)(c0 + orow) * R + r0 + cc4) = o;
        }
    } else {                                   // W2t[e][c][h] = W2[e][h][c], pad
        const int e = b - 200;                 // 0..15
        const int h = t;                       // 0..255
#pragma unroll
        for (int c = 0; c < 16; ++c) {
            W2t[(size_t)(e * 16 + c) * HEXP + h] =
                (c < NC) ? f2bf(W2[((size_t)e * HEXP + h) * NC + c]) : (unsigned short)0;
        }
    }
}

// ---------------------------------------------------------------------------
// Kernel 1 (round-7/10 exact, verified best): FUSED hb-GEMM + z-partial-GEMM.
// BM=128 x BN=256, BK=64, 4 waves 2x2, wave tile 64x128, B dbuf via async
// global_load_lds issued a step early, A reg-prefetched, 80 KB LDS,
// grid 512 = 2 blocks/CU. Epilogue: relu(acc+bias) -> swizzled bf16 LDS tile
// (aliases dead As/Bs), then per-wave z-partial over this block's 256
// hb-columns -> zpart[n-half]. hb never touches HBM.
// ---------------------------------------------------------------------------
__launch_bounds__(256, 2)
__global__ void gemm1(const float* __restrict__ X,
                      const unsigned short* __restrict__ Bt,   // enc_Wt [512][1024]
                      const float* __restrict__ enc_b,
                      const unsigned short* __restrict__ zWt,  // [64][512]
                      float* __restrict__ zpart) {             // [2][32768][64]
    __shared__ union G1U {
        struct {
            unsigned short As[128][64];       // 16 KB, single-buffered
            unsigned short Bs[2][256][64];    // 64 KB, double-buffered
        } s;
        unsigned short hbs[128][256];         // 64 KB epilogue hb tile
    } u;
    const int t = threadIdx.x;
    const int lane = t & 63;
    const int w = t >> 6;
    const int g = lane >> 4;
    const int l15 = lane & 15;
    const int l7 = l15 & 7;
    const int wm = (w >> 1) * 64;        // wave row base (0/64)
    const int wn = (w & 1) * 128;        // wave col base (0/128)

    // bijective XCD swizzle: nwg=512, 8 XCDs
    const int bid = blockIdx.x;
    const int wgid = (bid & 7) * 64 + (bid >> 3);
    const int m0 = (wgid >> 1) * 128;
    const int n0 = (wgid & 1) * 256;

    // A staging lanes: thread covers rows (t>>4)+16*it, cols (t&15)*4
    const int arow = t >> 4, acolq = t & 15;
    const float* aptr = X + (size_t)(m0 + arow) * DIM + acolq * 4;
    const int ascol = SWZ(acolq * 4, arow);           // swizzled dest col (elems)
    // B gload_lds lanes: 1KB chunk = 8 rows x 64 cols bf16; source pre-swizzled
    const int brow0 = lane >> 3;
    const int bsrccol = SWZ((lane & 7) * 8, brow0);
    const unsigned short* bptr = Bt + (size_t)(n0 + brow0) * DIM + bsrccol;

    f32x4 acc[4][8];
#pragma unroll
    for (int i = 0; i < 4; ++i)
#pragma unroll
        for (int j = 0; j < 8; ++j) acc[i][j] = f32x4{0.f, 0.f, 0.f, 0.f};

    // prologue: stage step 0 (B into buf 0, A into As)
    {
#pragma unroll
        for (int it = 0; it < 8; ++it) {
            const int chunk = it * 4 + w;           // 32 chunks of 8 rows
            gload_lds16(&u.s.Bs[0][chunk * 8][0], bptr + (size_t)chunk * 8 * DIM);
        }
        float4 a[8];
#pragma unroll
        for (int it = 0; it < 8; ++it)
            a[it] = *(const float4*)(aptr + (size_t)it * 16 * DIM);
#pragma unroll
        for (int it = 0; it < 8; ++it) {
            u16x4 p;
            p[0] = f2bf(a[it].x); p[1] = f2bf(a[it].y);
            p[2] = f2bf(a[it].z); p[3] = f2bf(a[it].w);
            *(u16x4*)&u.s.As[it * 16 + arow][ascol] = p;
        }
    }
    __syncthreads();

    float4 an[8];
    for (int step = 0; step < 16; ++step) {
        const int cur = step & 1, nxt = cur ^ 1;

        // issue next-step staging FIRST: B -> Bs[nxt] (async LDS), A -> regs
        if (step < 15) {
            const int k1 = (step + 1) * 64;
#pragma unroll
            for (int it = 0; it < 8; ++it) {
                const int chunk = it * 4 + w;
                gload_lds16(&u.s.Bs[nxt][chunk * 8][0],
                            bptr + (size_t)chunk * 8 * DIM + k1);
            }
#pragma unroll
            for (int it = 0; it < 8; ++it)
                an[it] = *(const float4*)(aptr + (size_t)it * 16 * DIM + k1);
        }

        // compute on current buffers: 2 kk halves x (4 row x 8 col) MFMA
#pragma unroll
        for (int kk = 0; kk < 2; ++kk) {
            const int ko = kk * 32 + g * 8;
            const int sko = SWZ(ko, l7);
            bf16x8 af[4], bfr[8];
#pragma unroll
            for (int i = 0; i < 4; ++i)
                af[i] = *(const bf16x8*)&u.s.As[wm + i * 16 + l15][sko];
#pragma unroll
            for (int j = 0; j < 8; ++j)
                bfr[j] = *(const bf16x8*)&u.s.Bs[cur][wn + j * 16 + l15][sko];
#pragma unroll
            for (int i = 0; i < 4; ++i)
#pragma unroll
                for (int j = 0; j < 8; ++j)
                    acc[i][j] = __builtin_amdgcn_mfma_f32_16x16x32_bf16(af[i], bfr[j], acc[i][j], 0, 0, 0);
        }
        __syncthreads();   // barrier1: As reads done; Bs[nxt] vmcnt drained

        // overwrite As with next step's A (X latency consumed by the MFMAs)
        if (step < 15) {
#pragma unroll
            for (int it = 0; it < 8; ++it) {
                u16x4 p;
                p[0] = f2bf(an[it].x); p[1] = f2bf(an[it].y);
                p[2] = f2bf(an[it].z); p[3] = f2bf(an[it].w);
                *(u16x4*)&u.s.As[it * 16 + arow][ascol] = p;
            }
        }
        __syncthreads();   // barrier2: As ready for next step
    }

    // ---- fused epilogue part 1: relu(acc+bias) -> swizzled bf16 LDS tile ----
#pragma unroll
    for (int j = 0; j < 8; ++j) {
        const int col = wn + j * 16 + l15;            // local col 0..255
        const float bias = enc_b[n0 + col];
#pragma unroll
        for (int i = 0; i < 4; ++i) {
            const int rb = wm + i * 16 + g * 4;
#pragma unroll
            for (int r = 0; r < 4; ++r) {
                float v = acc[i][j][r] + bias;
                v = v > 0.f ? v : 0.f;
                u.hbs[rb + r][SWZ(col, rb + r)] = f2bf(v);
            }
        }
    }
    __syncthreads();

    // ---- fused epilogue part 2: z-partial = hbs @ zWt[:, n0:n0+256] ----
    // wave w: rows w*32..w*32+31 (local), all 64 z-cols, K=256.
    {
        f32x4 zacc[2][4];
#pragma unroll
        for (int i2 = 0; i2 < 2; ++i2)
#pragma unroll
            for (int j2 = 0; j2 < 4; ++j2) zacc[i2][j2] = f32x4{0.f, 0.f, 0.f, 0.f};

        const unsigned short* zwB = zWt + n0;         // k-offset into [64][512]
#pragma unroll
        for (int ks = 0; ks < 8; ++ks) {
            const int k = ks * 32 + g * 8;            // local k 0..255
            bf16x8 bz[4];
#pragma unroll
            for (int j2 = 0; j2 < 4; ++j2)
                bz[j2] = *(const bf16x8*)(zwB + (size_t)(j2 * 16 + l15) * HENC + k);
#pragma unroll
            for (int i2 = 0; i2 < 2; ++i2) {
                const int row = w * 32 + i2 * 16 + l15;
                bf16x8 af = *(const bf16x8*)&u.hbs[row][SWZ(k, row)];
#pragma unroll
                for (int j2 = 0; j2 < 4; ++j2)
                    zacc[i2][j2] = __builtin_amdgcn_mfma_f32_16x16x32_bf16(af, bz[j2], zacc[i2][j2], 0, 0, 0);
            }
        }
        // store partial (f32). C layout: col=l15, row=g*4+r
        float* zp = zpart + (size_t)(n0 ? 1 : 0) * N_ROWS * NZ;
#pragma unroll
        for (int i2 = 0; i2 < 2; ++i2)
#pragma unroll
            for (int j2 = 0; j2 < 4; ++j2) {
                const int colz = j2 * 16 + l15;
#pragma unroll
                for (int r = 0; r < 4; ++r) {
                    const int rowz = m0 + w * 32 + i2 * 16 + g * 4 + r;
                    zp[(size_t)rowz * NZ + colz] = zacc[i2][j2][r];
                }
            }
    }
}

// ---------------------------------------------------------------------------
// Kernel 3 (round-7/10 exact, verified ~33 us): fused q + experts + combine.
// 512 blocks x 64 rows, 4 waves x 16 rows. P0 sums the two z-partials + z_b.
// W1 staged in LDS double-buffered at half-expert granularity via async
// global_load_lds; W2/b1 frags direct from L2 hoisted to expert-top;
// eh per-wave (wave-local LDS, no barrier). Static register indexing only.
// ---------------------------------------------------------------------------
__launch_bounds__(256, 2)
__global__ void expert_kernel(const float* __restrict__ zpart,  // [2][32768][64]
                              const float* __restrict__ z_b,
                              const float* __restrict__ mu,
                              const unsigned short* __restrict__ W1t,  // [16][256][64]
                              const float* __restrict__ b1,
                              const unsigned short* __restrict__ W2t,  // [16][16][256]
                              const float* __restrict__ b2,
                              float* __restrict__ out) {
    __shared__ __align__(16) union SU {
        struct {
            float zs[64][68];    // padded: row stride 68 dwords == 4 mod 32
            float mus[16][68];
            float rn[64];
            float mun[16];
        } a;                                         // ~22.1 KB
        struct {
            unsigned short w1s[2][128][64];          // 32 KB double-buffered W1 halves
            unsigned short ehs[4][16][136];          // per-wave eh, 17.4 KB
        } b;
    } su;
    __shared__ float qs[64][16];                     // 4 KB

    const int t = threadIdx.x;
    const int lane = t & 63;
    const int w = t >> 6;
    const int g = lane >> 4;
    const int l15 = lane & 15;
    const int l7 = l15 & 7;
    const int r0 = blockIdx.x * 64;

    // P0: z = zpart0 + zpart1 + z_b (64x64 f32) + mu into padded LDS
    {
        const float* zp0 = zpart;
        const float* zp1 = zpart + (size_t)N_ROWS * NZ;
#pragma unroll
        for (int it = 0; it < 4; ++it) {
            int idx = it * 256 + t;              // 1024 float4-slots
            int r = idx >> 4, c = (idx & 15) * 4;
            float4 a = *(const float4*)(zp0 + (size_t)(r0 + r) * NZ + c);
            float4 b = *(const float4*)(zp1 + (size_t)(r0 + r) * NZ + c);
            float4 zb = *(const float4*)(z_b + c);
            float4 s;
            s.x = a.x + b.x + zb.x; s.y = a.y + b.y + zb.y;
            s.z = a.z + b.z + zb.z; s.w = a.w + b.w + zb.w;
            *(float4*)&su.a.zs[r][c] = s;
        }
        int r = t >> 4, c = (t & 15) * 4;        // 256 float4-slots for mu
        *(float4*)&su.a.mus[r][c] = *(const float4*)(mu + (size_t)r * NZ + c);
    }
    __syncthreads();

    // P1a: row norms |z|^2 (t<64) and |mu|^2 (t in 64..79)
    if (t < 64) {
        float s = 0.f;
#pragma unroll
        for (int dq = 0; dq < 16; ++dq) {
            float4 v = *(const float4*)&su.a.zs[t][dq * 4];
            s += v.x * v.x + v.y * v.y + v.z * v.z + v.w * v.w;
        }
        su.a.rn[t] = s;
    } else if (t < 80) {
        int k = t - 64;
        float s = 0.f;
#pragma unroll
        for (int dq = 0; dq < 16; ++dq) {
            float4 v = *(const float4*)&su.a.mus[k][dq * 4];
            s += v.x * v.x + v.y * v.y + v.z * v.z + v.w * v.w;
        }
        su.a.mun[k] = s;
    }
    __syncthreads();

    // P1b: z fragments (kept for expert GEMMs) + dist via MFMA -> raw q
    bf16x8 az[2];
#pragma unroll
    for (int ks = 0; ks < 2; ++ks) {
        int row = w * 16 + l15;
        int ko = ks * 32 + g * 8;
        float4 lo = *(const float4*)&su.a.zs[row][ko];
        float4 hi = *(const float4*)&su.a.zs[row][ko + 4];
        u16x8 tmp;
        tmp[0] = f2bf(lo.x); tmp[1] = f2bf(lo.y); tmp[2] = f2bf(lo.z); tmp[3] = f2bf(lo.w);
        tmp[4] = f2bf(hi.x); tmp[5] = f2bf(hi.y); tmp[6] = f2bf(hi.z); tmp[7] = f2bf(hi.w);
        az[ks] = __builtin_bit_cast(bf16x8, tmp);
    }
    {
        bf16x8 bmu[2];
#pragma unroll
        for (int ks = 0; ks < 2; ++ks) {
            int ko = ks * 32 + g * 8;
            float4 lo = *(const float4*)&su.a.mus[l15][ko];
            float4 hi = *(const float4*)&su.a.mus[l15][ko + 4];
            u16x8 tmp;
            tmp[0] = f2bf(lo.x); tmp[1] = f2bf(lo.y); tmp[2] = f2bf(lo.z); tmp[3] = f2bf(lo.w);
            tmp[4] = f2bf(hi.x); tmp[5] = f2bf(hi.y); tmp[6] = f2bf(hi.z); tmp[7] = f2bf(hi.w);
            bmu[ks] = __builtin_bit_cast(bf16x8, tmp);
        }
        f32x4 dacc = f32x4{0.f, 0.f, 0.f, 0.f};
#pragma unroll
        for (int ks = 0; ks < 2; ++ks)
            dacc = __builtin_amdgcn_mfma_f32_16x16x32_bf16(az[ks], bmu[ks], dacc, 0, 0, 0);
#pragma unroll
        for (int r = 0; r < 4; ++r) {
            int rl = w * 16 + g * 4 + r;
            float dist = su.a.rn[rl] - 2.f * dacc[r] + su.a.mun[l15];
            qs[rl][l15] = 1.f / (1.f + dist);
        }
    }
    __syncthreads();

    // P1c: normalize q per row
    if (t < 64) {
        float s = 0.f;
#pragma unroll
        for (int k = 0; k < KE; ++k) s += qs[t][k];
        float inv = 1.f / s;
#pragma unroll
        for (int k = 0; k < KE; ++k) qs[t][k] *= inv;
    }
    __syncthreads();   // qs final, zs dead -> w1s/ehs may alias su.a

    // P3: expert loop with pipelined LDS weight staging.
    const int srow = lane >> 3;                       // 0..7 (row within chunk)
    const int scol = SWZ((lane & 7) * 8, srow);       // pre-swizzled source col

    // prologue: stage half 0 (expert 0, h0) into buf 0
#pragma unroll
    for (int it = 0; it < 4; ++it) {
        const int chunk = it * 4 + w;                 // 16 chunks of 8 rows
        gload_lds16(&su.b.w1s[0][chunk * 8][0],
                    W1t + (size_t)(chunk * 8 + srow) * NZ + scol);
    }
    __syncthreads();                                  // half0 staged

    float pacc[4] = {0.f, 0.f, 0.f, 0.f};
    unsigned short* eh = &su.b.ehs[w][0][0];          // per-wave [16][136]

    for (int e = 0; e < KE; ++e) {
        // expert-top: preload W2 frags + b1 (independent L2 loads, pipelined)
        const unsigned short* w2e = W2t + e * (16 * HEXP);
        bf16x8 w2f[8];
#pragma unroll
        for (int hh = 0; hh < 8; ++hh)
            w2f[hh] = *(const bf16x8*)(w2e + (size_t)l15 * HEXP + hh * 32 + g * 8);
        float b1v[2][8];
#pragma unroll
        for (int half = 0; half < 2; ++half)
#pragma unroll
            for (int j = 0; j < 8; ++j)
                b1v[half][j] = b1[e * HEXP + half * 128 + j * 16 + l15];

        f32x4 la = f32x4{0.f, 0.f, 0.f, 0.f};
#pragma unroll
        for (int half = 0; half < 2; ++half) {
            const int i = e * 2 + half;               // global half index 0..31
            const int cur = i & 1, nxt = cur ^ 1;

            // issue NEXT half's stage first (hidden under this half's MFMAs)
            if (i + 1 < 2 * KE) {
                const int eg = (i + 1) >> 1;
                const int h1 = ((i + 1) & 1) * 128;
                const unsigned short* src =
                    W1t + (size_t)eg * (HEXP * NZ) + (size_t)(h1 + srow) * NZ + scol;
#pragma unroll
                for (int it = 0; it < 4; ++it) {
                    const int chunk = it * 4 + w;
                    gload_lds16(&su.b.w1s[nxt][chunk * 8][0],
                                src + (size_t)chunk * 8 * NZ);
                }
            }

            // eh = relu(z @ W1half + b1) : 16 rows x 128 h, from staged LDS
            f32x4 ea[8];
#pragma unroll
            for (int j = 0; j < 8; ++j) ea[j] = f32x4{0.f, 0.f, 0.f, 0.f};
#pragma unroll
            for (int ks = 0; ks < 2; ++ks) {
                const int sko = SWZ(ks * 32 + g * 8, l7);
#pragma unroll
                for (int j = 0; j < 8; ++j) {
                    bf16x8 bw = *(const bf16x8*)&su.b.w1s[cur][j * 16 + l15][sko];
                    ea[j] = __builtin_amdgcn_mfma_f32_16x16x32_bf16(az[ks], bw, ea[j], 0, 0, 0);
                }
            }
            // bias + relu + bf16 -> per-wave LDS (transpose round-trip)
#pragma unroll
            for (int j = 0; j < 8; ++j) {
#pragma unroll
                for (int r = 0; r < 4; ++r) {
                    float v = ea[j][r] + b1v[half][j];
                    v = v > 0.f ? v : 0.f;
                    eh[(g * 4 + r) * 136 + j * 16 + l15] = f2bf(v);
                }
            }
            // logits partial over this half's 128 h (wave-local read-back)
#pragma unroll
            for (int ks2 = 0; ks2 < 4; ++ks2) {
                bf16x8 ef = *(const bf16x8*)&eh[l15 * 136 + ks2 * 32 + g * 8];
                la = __builtin_amdgcn_mfma_f32_16x16x32_bf16(ef, w2f[half * 4 + ks2], la, 0, 0, 0);
            }
            __syncthreads();   // drains next-half stage; WAR-protects buffers
        }

        // combine: preds += q[:,e] * (logits + b2[e])
        float b2v = (l15 < NC) ? b2[e * NC + l15] : 0.f;
#pragma unroll
        for (int r = 0; r < 4; ++r) {
            int rl = w * 16 + g * 4 + r;
            pacc[r] += qs[rl][e] * (la[r] + b2v);
        }
    }

    // P4: store preds
    if (l15 < NC) {
#pragma unroll
        for (int r = 0; r < 4; ++r) {
            int row = r0 + w * 16 + g * 4 + r;
            out[(size_t)row * NC + l15] = pacc[r];
        }
    }
}

// ---------------------------------------------------------------------------
extern "C" void kernel_launch(void* const* d_in, const int* in_sizes, int n_in,
                              void* d_out, int out_size, void* d_ws, size_t ws_size,
                              hipStream_t stream) {
    const float* X     = (const float*)d_in[0];
    const float* enc_W = (const float*)d_in[1];
    const float* enc_b = (const float*)d_in[2];
    const float* z_W   = (const float*)d_in[3];
    const float* z_b   = (const float*)d_in[4];
    const float* mu    = (const float*)d_in[5];
    const float* W1    = (const float*)d_in[6];
    const float* b1    = (const float*)d_in[7];
    const float* W2    = (const float*)d_in[8];
    const float* b2    = (const float*)d_in[9];
    float* out = (float*)d_out;

    // workspace layout (~18.5 MB)
    char* ws = (char*)d_ws;
    float*          zpart  = (float*)(ws);                       // 16,777,216 B
    unsigned short* enc_Wt = (unsigned short*)(ws + 16777216);   //  1,048,576 B
    unsigned short* z_Wt   = (unsigned short*)(ws + 17825792);   //     65,536 B
    unsigned short* W1t    = (unsigned short*)(ws + 17891328);   //    524,288 B
    unsigned short* W2t    = (unsigned short*)(ws + 18415616);   //    131,072 B

    prep_weights<<<dim3(216), dim3(256), 0, stream>>>(enc_W, z_W, W1, W2,
                                                      enc_Wt, z_Wt, W1t, W2t);
    gemm1<<<dim3(512), dim3(256), 0, stream>>>(X, enc_Wt, enc_b, z_Wt, zpart);
    expert_kernel<<<dim3(512), dim3(256), 0, stream>>>(zpart, z_b, mu, W1t, b1, W2t, b2, out);
}

// Round 16
// 120.610 us; speedup vs baseline: 1.3109x; 1.0051x over previous
//
#include <hip/hip_runtime.h>
#include <stdint.h>

// Problem constants
#define N_ROWS 32768
#define DIM    1024
#define HENC   512
#define NZ     64
#define KE     16
#define HEXP   256
#define NC     10

typedef __attribute__((ext_vector_type(8))) __bf16 bf16x8;
typedef __attribute__((ext_vector_type(4))) float f32x4;
typedef __attribute__((ext_vector_type(8))) unsigned short u16x8;
typedef __attribute__((ext_vector_type(4))) unsigned short u16x4;

__device__ __forceinline__ unsigned short f2bf(float f) {
    __bf16 h = (__bf16)f;  // RNE convert
    return __builtin_bit_cast(unsigned short, h);
}

// async global->LDS, 16B per lane. LDS dst must be wave-uniform (HW adds lane*16).
__device__ __forceinline__ void gload_lds16(void* lds, const void* gsrc) {
    __builtin_amdgcn_global_load_lds(
        (const __attribute__((address_space(1))) unsigned int*)gsrc,
        (__attribute__((address_space(3))) unsigned int*)lds,
        16, 0, 0);
}

// XOR swizzle in bf16-element space: flips 16B-granule bits 3..5 by row&7.
// Applied identically on write (or pre-swizzled global src) and read.
#define SWZ(col, row) ((col) ^ (((row) & 7) << 3))

// ---------------------------------------------------------------------------
// Kernel 0: coalesced cast+transpose via 64x64 LDS tiles (round-10).
// Blocks 0..127: enc_W[1024][512] -> enc_Wt[512][1024]. 128..135: z_W ->
// z_Wt. 136..199: W1[e] -> W1t[e]. 200..215: W2t scalar path (tiny).
// ---------------------------------------------------------------------------
__global__ void prep_weights(const float* __restrict__ enc_W,
                             const float* __restrict__ z_W,
                             const float* __restrict__ W1,
                             const float* __restrict__ W2,
                             unsigned short* __restrict__ enc_Wt,
                             unsigned short* __restrict__ z_Wt,
                             unsigned short* __restrict__ W1t,
                             unsigned short* __restrict__ W2t) {
    const int b = blockIdx.x;
    const int t = threadIdx.x;

    if (b < 200) {
        __shared__ float tile[64][65];
        const float* src;
        unsigned short* dst;
        int R, C, r0, c0;
        if (b < 128) {                         // enc_W [1024][512] -> enc_Wt
            src = enc_W; dst = enc_Wt; R = 1024; C = 512;
            r0 = (b >> 3) * 64; c0 = (b & 7) * 64;
        } else if (b < 136) {                  // z_W [512][64] -> z_Wt
            src = z_W; dst = z_Wt; R = 512; C = 64;
            r0 = (b - 128) * 64; c0 = 0;
        } else {                               // W1[e] [64][256] -> W1t[e]
            int i = b - 136, e = i >> 2, ht = i & 3;
            src = W1 + (size_t)e * (NZ * HEXP);
            dst = W1t + (size_t)e * (HEXP * NZ);
            R = 64; C = 256; r0 = 0; c0 = ht * 64;
        }
        const int rr = t >> 4, cc4 = (t & 15) * 4;
#pragma unroll
        for (int p = 0; p < 4; ++p) {
            float4 v = *(const float4*)(src + (size_t)(r0 + p * 16 + rr) * C + c0 + cc4);
            tile[p * 16 + rr][cc4 + 0] = v.x;
            tile[p * 16 + rr][cc4 + 1] = v.y;
            tile[p * 16 + rr][cc4 + 2] = v.z;
            tile[p * 16 + rr][cc4 + 3] = v.w;
        }
        __syncthreads();
        // Out[c0+orow][r0+cc4+q] = In[r0+cc4+q][c0+orow] = tile[cc4+q][orow]
#pragma unroll
        for (int p = 0; p < 4; ++p) {
            const int orow = p * 16 + rr;
            u16x4 o;
            o[0] = f2bf(tile[cc4 + 0][orow]);
            o[1] = f2bf(tile[cc4 + 1][orow]);
            o[2] = f2bf(tile[cc4 + 2][orow]);
            o[3] = f2bf(tile[cc4 + 3][orow]);
            *(u16x4*)(dst + (size_t)(c0 + orow) * R + r0 + cc4) = o;
        }
    } else {                                   // W2t[e][c][h] = W2[e][h][c], pad
        const int e = b - 200;                 // 0..15
        const int h = t;                       // 0..255
#pragma unroll
        for (int c = 0; c < 16; ++c) {
            W2t[(size_t)(e * 16 + c) * HEXP + h] =
                (c < NC) ? f2bf(W2[((size_t)e * HEXP + h) * NC + c]) : (unsigned short)0;
        }
    }
}

// ---------------------------------------------------------------------------
// Kernel 1 (round-7/10 exact, verified best): FUSED hb-GEMM + z-partial-GEMM.
// BM=128 x BN=256, BK=64, 4 waves 2x2, wave tile 64x128, B dbuf via async
// global_load_lds issued a step early, A reg-prefetched, 80 KB LDS,
// grid 512 = 2 blocks/CU. Epilogue: relu(acc+bias) -> swizzled bf16 LDS tile
// (aliases dead As/Bs), then per-wave z-partial over this block's 256
// hb-columns -> zpart[n-half]. hb never touches HBM.
// ---------------------------------------------------------------------------
__launch_bounds__(256, 2)
__global__ void gemm1(const float* __restrict__ X,
                      const unsigned short* __restrict__ Bt,   // enc_Wt [512][1024]
                      const float* __restrict__ enc_b,
                      const unsigned short* __restrict__ zWt,  // [64][512]
                      float* __restrict__ zpart) {             // [2][32768][64]
    __shared__ union G1U {
        struct {
            unsigned short As[128][64];       // 16 KB, single-buffered
            unsigned short Bs[2][256][64];    // 64 KB, double-buffered
        } s;
        unsigned short hbs[128][256];         // 64 KB epilogue hb tile
    } u;
    const int t = threadIdx.x;
    const int lane = t & 63;
    const int w = t >> 6;
    const int g = lane >> 4;
    const int l15 = lane & 15;
    const int l7 = l15 & 7;
    const int wm = (w >> 1) * 64;        // wave row base (0/64)
    const int wn = (w & 1) * 128;        // wave col base (0/128)

    // bijective XCD swizzle: nwg=512, 8 XCDs
    const int bid = blockIdx.x;
    const int wgid = (bid & 7) * 64 + (bid >> 3);
    const int m0 = (wgid >> 1) * 128;
    const int n0 = (wgid & 1) * 256;

    // A staging lanes: thread covers rows (t>>4)+16*it, cols (t&15)*4
    const int arow = t >> 4, acolq = t & 15;
    const float* aptr = X + (size_t)(m0 + arow) * DIM + acolq * 4;
    const int ascol = SWZ(acolq * 4, arow);           // swizzled dest col (elems)
    // B gload_lds lanes: 1KB chunk = 8 rows x 64 cols bf16; source pre-swizzled
    const int brow0 = lane >> 3;
    const int bsrccol = SWZ((lane & 7) * 8, brow0);
    const unsigned short* bptr = Bt + (size_t)(n0 + brow0) * DIM + bsrccol;

    f32x4 acc[4][8];
#pragma unroll
    for (int i = 0; i < 4; ++i)
#pragma unroll
        for (int j = 0; j < 8; ++j) acc[i][j] = f32x4{0.f, 0.f, 0.f, 0.f};

    // prologue: stage step 0 (B into buf 0, A into As)
    {
#pragma unroll
        for (int it = 0; it < 8; ++it) {
            const int chunk = it * 4 + w;           // 32 chunks of 8 rows
            gload_lds16(&u.s.Bs[0][chunk * 8][0], bptr + (size_t)chunk * 8 * DIM);
        }
        float4 a[8];
#pragma unroll
        for (int it = 0; it < 8; ++it)
            a[it] = *(const float4*)(aptr + (size_t)it * 16 * DIM);
#pragma unroll
        for (int it = 0; it < 8; ++it) {
            u16x4 p;
            p[0] = f2bf(a[it].x); p[1] = f2bf(a[it].y);
            p[2] = f2bf(a[it].z); p[3] = f2bf(a[it].w);
            *(u16x4*)&u.s.As[it * 16 + arow][ascol] = p;
        }
    }
    __syncthreads();

    float4 an[8];
    for (int step = 0; step < 16; ++step) {
        const int cur = step & 1, nxt = cur ^ 1;

        // issue next-step staging FIRST: B -> Bs[nxt] (async LDS), A -> regs
        if (step < 15) {
            const int k1 = (step + 1) * 64;
#pragma unroll
            for (int it = 0; it < 8; ++it) {
                const int chunk = it * 4 + w;
                gload_lds16(&u.s.Bs[nxt][chunk * 8][0],
                            bptr + (size_t)chunk * 8 * DIM + k1);
            }
#pragma unroll
            for (int it = 0; it < 8; ++it)
                an[it] = *(const float4*)(aptr + (size_t)it * 16 * DIM + k1);
        }

        // compute on current buffers: 2 kk halves x (4 row x 8 col) MFMA
#pragma unroll
        for (int kk = 0; kk < 2; ++kk) {
            const int ko = kk * 32 + g * 8;
            const int sko = SWZ(ko, l7);
            bf16x8 af[4], bfr[8];
#pragma unroll
            for (int i = 0; i < 4; ++i)
                af[i] = *(const bf16x8*)&u.s.As[wm + i * 16 + l15][sko];
#pragma unroll
            for (int j = 0; j < 8; ++j)
                bfr[j] = *(const bf16x8*)&u.s.Bs[cur][wn + j * 16 + l15][sko];
#pragma unroll
            for (int i = 0; i < 4; ++i)
#pragma unroll
                for (int j = 0; j < 8; ++j)
                    acc[i][j] = __builtin_amdgcn_mfma_f32_16x16x32_bf16(af[i], bfr[j], acc[i][j], 0, 0, 0);
        }
        __syncthreads();   // barrier1: As reads done; Bs[nxt] vmcnt drained

        // overwrite As with next step's A (X latency consumed by the MFMAs)
        if (step < 15) {
#pragma unroll
            for (int it = 0; it < 8; ++it) {
                u16x4 p;
                p[0] = f2bf(an[it].x); p[1] = f2bf(an[it].y);
                p[2] = f2bf(an[it].z); p[3] = f2bf(an[it].w);
                *(u16x4*)&u.s.As[it * 16 + arow][ascol] = p;
            }
        }
        __syncthreads();   // barrier2: As ready for next step
    }

    // ---- fused epilogue part 1: relu(acc+bias) -> swizzled bf16 LDS tile ----
#pragma unroll
    for (int j = 0; j < 8; ++j) {
        const int col = wn + j * 16 + l15;            // local col 0..255
        const float bias = enc_b[n0 + col];
#pragma unroll
        for (int i = 0; i < 4; ++i) {
            const int rb = wm + i * 16 + g * 4;
#pragma unroll
            for (int r = 0; r < 4; ++r) {
                float v = acc[i][j][r] + bias;
                v = v > 0.f ? v : 0.f;
                u.hbs[rb + r][SWZ(col, rb + r)] = f2bf(v);
            }
        }
    }
    __syncthreads();

    // ---- fused epilogue part 2: z-partial = hbs @ zWt[:, n0:n0+256] ----
    // wave w: rows w*32..w*32+31 (local), all 64 z-cols, K=256.
    {
        f32x4 zacc[2][4];
#pragma unroll
        for (int i2 = 0; i2 < 2; ++i2)
#pragma unroll
            for (int j2 = 0; j2 < 4; ++j2) zacc[i2][j2] = f32x4{0.f, 0.f, 0.f, 0.f};

        const unsigned short* zwB = zWt + n0;         // k-offset into [64][512]
#pragma unroll
        for (int ks = 0; ks < 8; ++ks) {
            const int k = ks * 32 + g * 8;            // local k 0..255
            bf16x8 bz[4];
#pragma unroll
            for (int j2 = 0; j2 < 4; ++j2)
                bz[j2] = *(const bf16x8*)(zwB + (size_t)(j2 * 16 + l15) * HENC + k);
#pragma unroll
            for (int i2 = 0; i2 < 2; ++i2) {
                const int row = w * 32 + i2 * 16 + l15;
                bf16x8 af = *(const bf16x8*)&u.hbs[row][SWZ(k, row)];
#pragma unroll
                for (int j2 = 0; j2 < 4; ++j2)
                    zacc[i2][j2] = __builtin_amdgcn_mfma_f32_16x16x32_bf16(af, bz[j2], zacc[i2][j2], 0, 0, 0);
            }
        }
        // store partial (f32). C layout: col=l15, row=g*4+r
        float* zp = zpart + (size_t)(n0 ? 1 : 0) * N_ROWS * NZ;
#pragma unroll
        for (int i2 = 0; i2 < 2; ++i2)
#pragma unroll
            for (int j2 = 0; j2 < 4; ++j2) {
                const int colz = j2 * 16 + l15;
#pragma unroll
                for (int r = 0; r < 4; ++r) {
                    const int rowz = m0 + w * 32 + i2 * 16 + g * 4 + r;
                    zp[(size_t)rowz * NZ + colz] = zacc[i2][j2][r];
                }
            }
    }
}

// ---------------------------------------------------------------------------
// Kernel 3 (ROUND-16): fused q + experts + combine, DELAYED-LOGITS pipeline
// with STATIC register indexing (r9's algorithm, rule-20-safe this time:
// both half-slots written out explicitly, so every b1v/w2f index is a
// compile-time literal). Per slot: [logits of PREVIOUS half from ping-pong
// eh LDS -- its writes were drained by the previous barrier, so the read is
// latency-free] [stage next W1 half via async glds] [ehGEMM] [eh write]
// [barrier]. The eh ds_write->lgkmcnt->ds_read chain no longer sits inside
// the slot. W1 dbuf + W2/b1 direct-from-L2 unchanged. LDS ~71.6 KB ->
// 2 blocks/CU. gemm1/prep are the verified-best round-10 versions.
// ---------------------------------------------------------------------------
__launch_bounds__(256, 2)
__global__ void expert_kernel(const float* __restrict__ zpart,  // [2][32768][64]
                              const float* __restrict__ z_b,
                              const float* __restrict__ mu,
                              const unsigned short* __restrict__ W1t,  // [16][256][64]
                              const float* __restrict__ b1,
                              const unsigned short* __restrict__ W2t,  // [16][16][256]
                              const float* __restrict__ b2,
                              float* __restrict__ out) {
    __shared__ __align__(16) union SU {
        struct {
            float zs[64][68];    // padded: row stride 68 dwords == 4 mod 32
            float mus[16][68];
            float rn[64];
            float mun[16];
        } a;                                         // ~22.1 KB
        struct {
            unsigned short w1s[2][128][64];          // 32 KB double-buffered W1 halves
            unsigned short ehs[4][2][16][136];       // per-wave ping-pong eh, 34.8 KB
        } b;
    } su;
    __shared__ float qs[64][16];                     // 4 KB

    const int t = threadIdx.x;
    const int lane = t & 63;
    const int w = t >> 6;
    const int g = lane >> 4;
    const int l15 = lane & 15;
    const int l7 = l15 & 7;
    const int r0 = blockIdx.x * 64;

    // P0: z = zpart0 + zpart1 + z_b (64x64 f32) + mu into padded LDS
    {
        const float* zp0 = zpart;
        const float* zp1 = zpart + (size_t)N_ROWS * NZ;
#pragma unroll
        for (int it = 0; it < 4; ++it) {
            int idx = it * 256 + t;              // 1024 float4-slots
            int r = idx >> 4, c = (idx & 15) * 4;
            float4 a = *(const float4*)(zp0 + (size_t)(r0 + r) * NZ + c);
            float4 b = *(const float4*)(zp1 + (size_t)(r0 + r) * NZ + c);
            float4 zb = *(const float4*)(z_b + c);
            float4 s;
            s.x = a.x + b.x + zb.x; s.y = a.y + b.y + zb.y;
            s.z = a.z + b.z + zb.z; s.w = a.w + b.w + zb.w;
            *(float4*)&su.a.zs[r][c] = s;
        }
        int r = t >> 4, c = (t & 15) * 4;        // 256 float4-slots for mu
        *(float4*)&su.a.mus[r][c] = *(const float4*)(mu + (size_t)r * NZ + c);
    }
    __syncthreads();

    // P1a: row norms |z|^2 (t<64) and |mu|^2 (t in 64..79)
    if (t < 64) {
        float s = 0.f;
#pragma unroll
        for (int dq = 0; dq < 16; ++dq) {
            float4 v = *(const float4*)&su.a.zs[t][dq * 4];
            s += v.x * v.x + v.y * v.y + v.z * v.z + v.w * v.w;
        }
        su.a.rn[t] = s;
    } else if (t < 80) {
        int k = t - 64;
        float s = 0.f;
#pragma unroll
        for (int dq = 0; dq < 16; ++dq) {
            float4 v = *(const float4*)&su.a.mus[k][dq * 4];
            s += v.x * v.x + v.y * v.y + v.z * v.z + v.w * v.w;
        }
        su.a.mun[k] = s;
    }
    __syncthreads();

    // P1b: z fragments (kept for expert GEMMs) + dist via MFMA -> raw q
    bf16x8 az[2];
#pragma unroll
    for (int ks = 0; ks < 2; ++ks) {
        int row = w * 16 + l15;
        int ko = ks * 32 + g * 8;
        float4 lo = *(const float4*)&su.a.zs[row][ko];
        float4 hi = *(const float4*)&su.a.zs[row][ko + 4];
        u16x8 tmp;
        tmp[0] = f2bf(lo.x); tmp[1] = f2bf(lo.y); tmp[2] = f2bf(lo.z); tmp[3] = f2bf(lo.w);
        tmp[4] = f2bf(hi.x); tmp[5] = f2bf(hi.y); tmp[6] = f2bf(hi.z); tmp[7] = f2bf(hi.w);
        az[ks] = __builtin_bit_cast(bf16x8, tmp);
    }
    {
        bf16x8 bmu[2];
#pragma unroll
        for (int ks = 0; ks < 2; ++ks) {
            int ko = ks * 32 + g * 8;
            float4 lo = *(const float4*)&su.a.mus[l15][ko];
            float4 hi = *(const float4*)&su.a.mus[l15][ko + 4];
            u16x8 tmp;
            tmp[0] = f2bf(lo.x); tmp[1] = f2bf(lo.y); tmp[2] = f2bf(lo.z); tmp[3] = f2bf(lo.w);
            tmp[4] = f2bf(hi.x); tmp[5] = f2bf(hi.y); tmp[6] = f2bf(hi.z); tmp[7] = f2bf(hi.w);
            bmu[ks] = __builtin_bit_cast(bf16x8, tmp);
        }
        f32x4 dacc = f32x4{0.f, 0.f, 0.f, 0.f};
#pragma unroll
        for (int ks = 0; ks < 2; ++ks)
            dacc = __builtin_amdgcn_mfma_f32_16x16x32_bf16(az[ks], bmu[ks], dacc, 0, 0, 0);
#pragma unroll
        for (int r = 0; r < 4; ++r) {
            int rl = w * 16 + g * 4 + r;
            float dist = su.a.rn[rl] - 2.f * dacc[r] + su.a.mun[l15];
            qs[rl][l15] = 1.f / (1.f + dist);
        }
    }
    __syncthreads();

    // P1c: normalize q per row
    if (t < 64) {
        float s = 0.f;
#pragma unroll
        for (int k = 0; k < KE; ++k) s += qs[t][k];
        float inv = 1.f / s;
#pragma unroll
        for (int k = 0; k < KE; ++k) qs[t][k] *= inv;
    }
    __syncthreads();   // qs final, zs dead -> w1s/ehs may alias su.a

    // P3: expert loop, delayed-logits. All register-array indices static.
    const int srow = lane >> 3;                       // 0..7 (row within chunk)
    const int scol = SWZ((lane & 7) * 8, srow);       // pre-swizzled source col

    // prologue: stage (e=0, half0) into w1s[0]
#pragma unroll
    for (int it = 0; it < 4; ++it) {
        const int chunk = it * 4 + w;                 // 16 chunks of 8 rows
        gload_lds16(&su.b.w1s[0][chunk * 8][0],
                    W1t + (size_t)(chunk * 8 + srow) * NZ + scol);
    }
    __syncthreads();                                  // half0 staged

    float pacc[4] = {0.f, 0.f, 0.f, 0.f};
    f32x4 la = f32x4{0.f, 0.f, 0.f, 0.f};
    bf16x8 w2f[8];
    float b1v[2][8];
    unsigned short* eh0 = &su.b.ehs[w][0][0][0];      // ping (written even slots)
    unsigned short* eh1 = &su.b.ehs[w][1][0][0];      // pong (written odd slots)

    for (int e = 0; e < KE; ++e) {
        // =========== slot 2e (half 0) ===========
        // 1) logits for (e-1, half1): reads eh1 (drained by prev barrier),
        //    uses OLD w2f[4..7]; then combine expert e-1.
        if (e > 0) {
#pragma unroll
            for (int ks2 = 0; ks2 < 4; ++ks2) {
                bf16x8 ef = *(const bf16x8*)&eh1[l15 * 136 + ks2 * 32 + g * 8];
                la = __builtin_amdgcn_mfma_f32_16x16x32_bf16(ef, w2f[4 + ks2], la, 0, 0, 0);
            }
            float b2v = (l15 < NC) ? b2[(e - 1) * NC + l15] : 0.f;
#pragma unroll
            for (int r = 0; r < 4; ++r) {
                int rl = w * 16 + g * 4 + r;
                pacc[r] += qs[rl][e - 1] * (la[r] + b2v);
            }
            la = f32x4{0.f, 0.f, 0.f, 0.f};
        }
        // 2) stage (e, half1) into w1s[1] (drains at this slot's barrier)
        {
            const unsigned short* src =
                W1t + (size_t)e * (HEXP * NZ) + (size_t)(128 + srow) * NZ + scol;
#pragma unroll
            for (int it = 0; it < 4; ++it) {
                const int chunk = it * 4 + w;
                gload_lds16(&su.b.w1s[1][chunk * 8][0], src + (size_t)chunk * 8 * NZ);
            }
        }
        // 3) new w2f/b1 for expert e (consumed slots 2e+1 / 2e+2: full-slot cover)
        {
            const unsigned short* w2e = W2t + e * (16 * HEXP);
#pragma unroll
            for (int hh = 0; hh < 8; ++hh)
                w2f[hh] = *(const bf16x8*)(w2e + (size_t)l15 * HEXP + hh * 32 + g * 8);
#pragma unroll
            for (int j = 0; j < 8; ++j) {
                b1v[0][j] = b1[e * HEXP + j * 16 + l15];
                b1v[1][j] = b1[e * HEXP + 128 + j * 16 + l15];
            }
        }
        // 4) ehGEMM half0 from w1s[0]; bias+relu -> eh0
        {
            f32x4 ea[8];
#pragma unroll
            for (int j = 0; j < 8; ++j) ea[j] = f32x4{0.f, 0.f, 0.f, 0.f};
#pragma unroll
            for (int ks = 0; ks < 2; ++ks) {
                const int sko = SWZ(ks * 32 + g * 8, l7);
#pragma unroll
                for (int j = 0; j < 8; ++j) {
                    bf16x8 bw = *(const bf16x8*)&su.b.w1s[0][j * 16 + l15][sko];
                    ea[j] = __builtin_amdgcn_mfma_f32_16x16x32_bf16(az[ks], bw, ea[j], 0, 0, 0);
                }
            }
#pragma unroll
            for (int j = 0; j < 8; ++j) {
#pragma unroll
                for (int r = 0; r < 4; ++r) {
                    float v = ea[j][r] + b1v[0][j];
                    v = v > 0.f ? v : 0.f;
                    eh0[(g * 4 + r) * 136 + j * 16 + l15] = f2bf(v);
                }
            }
        }
        __syncthreads();

        // =========== slot 2e+1 (half 1) ===========
        // 1) logits for (e, half0): reads eh0, uses w2f[0..3] (no combine yet)
#pragma unroll
        for (int ks2 = 0; ks2 < 4; ++ks2) {
            bf16x8 ef = *(const bf16x8*)&eh0[l15 * 136 + ks2 * 32 + g * 8];
            la = __builtin_amdgcn_mfma_f32_16x16x32_bf16(ef, w2f[ks2], la, 0, 0, 0);
        }
        // 2) stage (e+1, half0) into w1s[0] (last read before prev barrier)
        if (e + 1 < KE) {
            const unsigned short* src =
                W1t + (size_t)(e + 1) * (HEXP * NZ) + (size_t)srow * NZ + scol;
#pragma unroll
            for (int it = 0; it < 4; ++it) {
                const int chunk = it * 4 + w;
                gload_lds16(&su.b.w1s[0][chunk * 8][0], src + (size_t)chunk * 8 * NZ);
            }
        }
        // 3) ehGEMM half1 from w1s[1]; bias+relu -> eh1
        {
            f32x4 ea[8];
#pragma unroll
            for (int j = 0; j < 8; ++j) ea[j] = f32x4{0.f, 0.f, 0.f, 0.f};
#pragma unroll
            for (int ks = 0; ks < 2; ++ks) {
                const int sko = SWZ(ks * 32 + g * 8, l7);
#pragma unroll
                for (int j = 0; j < 8; ++j) {
                    bf16x8 bw = *(const bf16x8*)&su.b.w1s[1][j * 16 + l15][sko];
                    ea[j] = __builtin_amdgcn_mfma_f32_16x16x32_bf16(az[ks], bw, ea[j], 0, 0, 0);
                }
            }
#pragma unroll
            for (int j = 0; j < 8; ++j) {
#pragma unroll
                for (int r = 0; r < 4; ++r) {
                    float v = ea[j][r] + b1v[1][j];
                    v = v > 0.f ? v : 0.f;
                    eh1[(g * 4 + r) * 136 + j * 16 + l15] = f2bf(v);
                }
            }
        }
        __syncthreads();
    }

    // epilogue: logits (KE-1, half1) + combine expert KE-1
    {
#pragma unroll
        for (int ks2 = 0; ks2 < 4; ++ks2) {
            bf16x8 ef = *(const bf16x8*)&eh1[l15 * 136 + ks2 * 32 + g * 8];
            la = __builtin_amdgcn_mfma_f32_16x16x32_bf16(ef, w2f[4 + ks2], la, 0, 0, 0);
        }
        float b2v = (l15 < NC) ? b2[(KE - 1) * NC + l15] : 0.f;
#pragma unroll
        for (int r = 0; r < 4; ++r) {
            int rl = w * 16 + g * 4 + r;
            pacc[r] += qs[rl][KE - 1] * (la[r] + b2v);
        }
    }

    // P4: store preds
    if (l15 < NC) {
#pragma unroll
        for (int r = 0; r < 4; ++r) {
            int row = r0 + w * 16 + g * 4 + r;
            out[(size_t)row * NC + l15] = pacc[r];
        }
    }
}

// ---------------------------------------------------------------------------
extern "C" void kernel_launch(void* const* d_in, const int* in_sizes, int n_in,
                              void* d_out, int out_size, void* d_ws, size_t ws_size,
                              hipStream_t stream) {
    const float* X     = (const float*)d_in[0];
    const float* enc_W = (const float*)d_in[1];
    const float* enc_b = (const float*)d_in[2];
    const float* z_W   = (const float*)d_in[3];
    const float* z_b   = (const float*)d_in[4];
    const float* mu    = (const float*)d_in[5];
    const float* W1    = (const float*)d_in[6];
    const float* b1    = (const float*)d_in[7];
    const float* W2    = (const float*)d_in[8];
    const float* b2    = (const float*)d_in[9];
    float* out = (float*)d_out;

    // workspace layout (~18.5 MB)
    char* ws = (char*)d_ws;
    float*          zpart  = (float*)(ws);                       // 16,777,216 B
    unsigned short* enc_Wt = (unsigned short*)(ws + 16777216);   //  1,048,576 B
    unsigned short* z_Wt   = (unsigned short*)(ws + 17825792);   //     65,536 B
    unsigned short* W1t    = (unsigned short*)(ws + 17891328);   //    524,288 B
    unsigned short* W2t    = (unsigned short*)(ws + 18415616);   //    131,072 B

    prep_weights<<<dim3(216), dim3(256), 0, stream>>>(enc_W, z_W, W1, W2,
                                                      enc_Wt, z_Wt, W1t, W2t);
    gemm1<<<dim3(512), dim3(256), 0, stream>>>(X, enc_Wt, enc_b, z_Wt, zpart);
    expert_kernel<<<dim3(512), dim3(256), 0, stream>>>(zpart, z_b, mu, W1t, b1, W2t, b2, out);
}

// Round 17
// 120.543 us; speedup vs baseline: 1.3116x; 1.0006x over previous
//
#include <hip/hip_runtime.h>
#include <stdint.h>

// Problem constants
#define N_ROWS 32768
#define DIM    1024
#define HENC   512
#define NZ     64
#define KE     16
#define HEXP   256
#define NC     10

typedef __attribute__((ext_vector_type(8))) __bf16 bf16x8;
typedef __attribute__((ext_vector_type(4))) float f32x4;
typedef __attribute__((ext_vector_type(8))) unsigned short u16x8;
typedef __attribute__((ext_vector_type(4))) unsigned short u16x4;

__device__ __forceinline__ unsigned short f2bf(float f) {
    __bf16 h = (__bf16)f;  // RNE convert
    return __builtin_bit_cast(unsigned short, h);
}

// async global->LDS, 16B per lane. LDS dst must be wave-uniform (HW adds lane*16).
__device__ __forceinline__ void gload_lds16(void* lds, const void* gsrc) {
    __builtin_amdgcn_global_load_lds(
        (const __attribute__((address_space(1))) unsigned int*)gsrc,
        (__attribute__((address_space(3))) unsigned int*)lds,
        16, 0, 0);
}

// XOR swizzle in bf16-element space: flips 16B-granule bits 3..5 by row&7.
// Applied identically on write (or pre-swizzled global src) and read.
#define SWZ(col, row) ((col) ^ (((row) & 7) << 3))

// ---------------------------------------------------------------------------
// Kernel 0: coalesced cast+transpose via 64x64 LDS tiles (round-10).
// Blocks 0..127: enc_W[1024][512] -> enc_Wt[512][1024]. 128..135: z_W ->
// z_Wt. 136..199: W1[e] -> W1t[e]. 200..215: W2t scalar path (tiny).
// ---------------------------------------------------------------------------
__global__ void prep_weights(const float* __restrict__ enc_W,
                             const float* __restrict__ z_W,
                             const float* __restrict__ W1,
                             const float* __restrict__ W2,
                             unsigned short* __restrict__ enc_Wt,
                             unsigned short* __restrict__ z_Wt,
                             unsigned short* __restrict__ W1t,
                             unsigned short* __restrict__ W2t) {
    const int b = blockIdx.x;
    const int t = threadIdx.x;

    if (b < 200) {
        __shared__ float tile[64][65];
        const float* src;
        unsigned short* dst;
        int R, C, r0, c0;
        if (b < 128) {                         // enc_W [1024][512] -> enc_Wt
            src = enc_W; dst = enc_Wt; R = 1024; C = 512;
            r0 = (b >> 3) * 64; c0 = (b & 7) * 64;
        } else if (b < 136) {                  // z_W [512][64] -> z_Wt
            src = z_W; dst = z_Wt; R = 512; C = 64;
            r0 = (b - 128) * 64; c0 = 0;
        } else {                               // W1[e] [64][256] -> W1t[e]
            int i = b - 136, e = i >> 2, ht = i & 3;
            src = W1 + (size_t)e * (NZ * HEXP);
            dst = W1t + (size_t)e * (HEXP * NZ);
            R = 64; C = 256; r0 = 0; c0 = ht * 64;
        }
        const int rr = t >> 4, cc4 = (t & 15) * 4;
#pragma unroll
        for (int p = 0; p < 4; ++p) {
            float4 v = *(const float4*)(src + (size_t)(r0 + p * 16 + rr) * C + c0 + cc4);
            tile[p * 16 + rr][cc4 + 0] = v.x;
            tile[p * 16 + rr][cc4 + 1] = v.y;
            tile[p * 16 + rr][cc4 + 2] = v.z;
            tile[p * 16 + rr][cc4 + 3] = v.w;
        }
        __syncthreads();
        // Out[c0+orow][r0+cc4+q] = In[r0+cc4+q][c0+orow] = tile[cc4+q][orow]
#pragma unroll
        for (int p = 0; p < 4; ++p) {
            const int orow = p * 16 + rr;
            u16x4 o;
            o[0] = f2bf(tile[cc4 + 0][orow]);
            o[1] = f2bf(tile[cc4 + 1][orow]);
            o[2] = f2bf(tile[cc4 + 2][orow]);
            o[3] = f2bf(tile[cc4 + 3][orow]);
            *(u16x4*)(dst + (size_t)(c0 + orow) * R + r0 + cc4) = o;
        }
    } else {                                   // W2t[e][c][h] = W2[e][h][c], pad
        const int e = b - 200;                 // 0..15
        const int h = t;                       // 0..255
#pragma unroll
        for (int c = 0; c < 16; ++c) {
            W2t[(size_t)(e * 16 + c) * HEXP + h] =
                (c < NC) ? f2bf(W2[((size_t)e * HEXP + h) * NC + c]) : (unsigned short)0;
        }
    }
}

// ---------------------------------------------------------------------------
// Kernel 1 (round-7/10 exact, verified best): FUSED hb-GEMM + z-partial-GEMM.
// BM=128 x BN=256, BK=64, 4 waves 2x2, wave tile 64x128, B dbuf via async
// global_load_lds issued a step early, A reg-prefetched, 80 KB LDS,
// grid 512 = 2 blocks/CU. Epilogue: relu(acc+bias) -> swizzled bf16 LDS tile
// (aliases dead As/Bs), then per-wave z-partial over this block's 256
// hb-columns -> zpart[n-half]. hb never touches HBM.
// ---------------------------------------------------------------------------
__launch_bounds__(256, 2)
__global__ void gemm1(const float* __restrict__ X,
                      const unsigned short* __restrict__ Bt,   // enc_Wt [512][1024]
                      const float* __restrict__ enc_b,
                      const unsigned short* __restrict__ zWt,  // [64][512]
                      float* __restrict__ zpart) {             // [2][32768][64]
    __shared__ union G1U {
        struct {
            unsigned short As[128][64];       // 16 KB, single-buffered
            unsigned short Bs[2][256][64];    // 64 KB, double-buffered
        } s;
        unsigned short hbs[128][256];         // 64 KB epilogue hb tile
    } u;
    const int t = threadIdx.x;
    const int lane = t & 63;
    const int w = t >> 6;
    const int g = lane >> 4;
    const int l15 = lane & 15;
    const int l7 = l15 & 7;
    const int wm = (w >> 1) * 64;        // wave row base (0/64)
    const int wn = (w & 1) * 128;        // wave col base (0/128)

    // bijective XCD swizzle: nwg=512, 8 XCDs
    const int bid = blockIdx.x;
    const int wgid = (bid & 7) * 64 + (bid >> 3);
    const int m0 = (wgid >> 1) * 128;
    const int n0 = (wgid & 1) * 256;

    // A staging lanes: thread covers rows (t>>4)+16*it, cols (t&15)*4
    const int arow = t >> 4, acolq = t & 15;
    const float* aptr = X + (size_t)(m0 + arow) * DIM + acolq * 4;
    const int ascol = SWZ(acolq * 4, arow);           // swizzled dest col (elems)
    // B gload_lds lanes: 1KB chunk = 8 rows x 64 cols bf16; source pre-swizzled
    const int brow0 = lane >> 3;
    const int bsrccol = SWZ((lane & 7) * 8, brow0);
    const unsigned short* bptr = Bt + (size_t)(n0 + brow0) * DIM + bsrccol;

    f32x4 acc[4][8];
#pragma unroll
    for (int i = 0; i < 4; ++i)
#pragma unroll
        for (int j = 0; j < 8; ++j) acc[i][j] = f32x4{0.f, 0.f, 0.f, 0.f};

    // prologue: stage step 0 (B into buf 0, A into As)
    {
#pragma unroll
        for (int it = 0; it < 8; ++it) {
            const int chunk = it * 4 + w;           // 32 chunks of 8 rows
            gload_lds16(&u.s.Bs[0][chunk * 8][0], bptr + (size_t)chunk * 8 * DIM);
        }
        float4 a[8];
#pragma unroll
        for (int it = 0; it < 8; ++it)
            a[it] = *(const float4*)(aptr + (size_t)it * 16 * DIM);
#pragma unroll
        for (int it = 0; it < 8; ++it) {
            u16x4 p;
            p[0] = f2bf(a[it].x); p[1] = f2bf(a[it].y);
            p[2] = f2bf(a[it].z); p[3] = f2bf(a[it].w);
            *(u16x4*)&u.s.As[it * 16 + arow][ascol] = p;
        }
    }
    __syncthreads();

    float4 an[8];
    for (int step = 0; step < 16; ++step) {
        const int cur = step & 1, nxt = cur ^ 1;

        // issue next-step staging FIRST: B -> Bs[nxt] (async LDS), A -> regs
        if (step < 15) {
            const int k1 = (step + 1) * 64;
#pragma unroll
            for (int it = 0; it < 8; ++it) {
                const int chunk = it * 4 + w;
                gload_lds16(&u.s.Bs[nxt][chunk * 8][0],
                            bptr + (size_t)chunk * 8 * DIM + k1);
            }
#pragma unroll
            for (int it = 0; it < 8; ++it)
                an[it] = *(const float4*)(aptr + (size_t)it * 16 * DIM + k1);
        }

        // compute on current buffers: 2 kk halves x (4 row x 8 col) MFMA
#pragma unroll
        for (int kk = 0; kk < 2; ++kk) {
            const int ko = kk * 32 + g * 8;
            const int sko = SWZ(ko, l7);
            bf16x8 af[4], bfr[8];
#pragma unroll
            for (int i = 0; i < 4; ++i)
                af[i] = *(const bf16x8*)&u.s.As[wm + i * 16 + l15][sko];
#pragma unroll
            for (int j = 0; j < 8; ++j)
                bfr[j] = *(const bf16x8*)&u.s.Bs[cur][wn + j * 16 + l15][sko];
#pragma unroll
            for (int i = 0; i < 4; ++i)
#pragma unroll
                for (int j = 0; j < 8; ++j)
                    acc[i][j] = __builtin_amdgcn_mfma_f32_16x16x32_bf16(af[i], bfr[j], acc[i][j], 0, 0, 0);
        }
        __syncthreads();   // barrier1: As reads done; Bs[nxt] vmcnt drained

        // overwrite As with next step's A (X latency consumed by the MFMAs)
        if (step < 15) {
#pragma unroll
            for (int it = 0; it < 8; ++it) {
                u16x4 p;
                p[0] = f2bf(an[it].x); p[1] = f2bf(an[it].y);
                p[2] = f2bf(an[it].z); p[3] = f2bf(an[it].w);
                *(u16x4*)&u.s.As[it * 16 + arow][ascol] = p;
            }
        }
        __syncthreads();   // barrier2: As ready for next step
    }

    // ---- fused epilogue part 1: relu(acc+bias) -> swizzled bf16 LDS tile ----
#pragma unroll
    for (int j = 0; j < 8; ++j) {
        const int col = wn + j * 16 + l15;            // local col 0..255
        const float bias = enc_b[n0 + col];
#pragma unroll
        for (int i = 0; i < 4; ++i) {
            const int rb = wm + i * 16 + g * 4;
#pragma unroll
            for (int r = 0; r < 4; ++r) {
                float v = acc[i][j][r] + bias;
                v = v > 0.f ? v : 0.f;
                u.hbs[rb + r][SWZ(col, rb + r)] = f2bf(v);
            }
        }
    }
    __syncthreads();

    // ---- fused epilogue part 2: z-partial = hbs @ zWt[:, n0:n0+256] ----
    // wave w: rows w*32..w*32+31 (local), all 64 z-cols, K=256.
    {
        f32x4 zacc[2][4];
#pragma unroll
        for (int i2 = 0; i2 < 2; ++i2)
#pragma unroll
            for (int j2 = 0; j2 < 4; ++j2) zacc[i2][j2] = f32x4{0.f, 0.f, 0.f, 0.f};

        const unsigned short* zwB = zWt + n0;         // k-offset into [64][512]
#pragma unroll
        for (int ks = 0; ks < 8; ++ks) {
            const int k = ks * 32 + g * 8;            // local k 0..255
            bf16x8 bz[4];
#pragma unroll
            for (int j2 = 0; j2 < 4; ++j2)
                bz[j2] = *(const bf16x8*)(zwB + (size_t)(j2 * 16 + l15) * HENC + k);
#pragma unroll
            for (int i2 = 0; i2 < 2; ++i2) {
                const int row = w * 32 + i2 * 16 + l15;
                bf16x8 af = *(const bf16x8*)&u.hbs[row][SWZ(k, row)];
#pragma unroll
                for (int j2 = 0; j2 < 4; ++j2)
                    zacc[i2][j2] = __builtin_amdgcn_mfma_f32_16x16x32_bf16(af, bz[j2], zacc[i2][j2], 0, 0, 0);
            }
        }
        // store partial (f32). C layout: col=l15, row=g*4+r
        float* zp = zpart + (size_t)(n0 ? 1 : 0) * N_ROWS * NZ;
#pragma unroll
        for (int i2 = 0; i2 < 2; ++i2)
#pragma unroll
            for (int j2 = 0; j2 < 4; ++j2) {
                const int colz = j2 * 16 + l15;
#pragma unroll
                for (int r = 0; r < 4; ++r) {
                    const int rowz = m0 + w * 32 + i2 * 16 + g * 4 + r;
                    zp[(size_t)rowz * NZ + colz] = zacc[i2][j2][r];
                }
            }
    }
}

// ---------------------------------------------------------------------------
// Kernel 3 (round-16, verified best): fused q + experts + combine,
// DELAYED-LOGITS pipeline with STATIC register indexing (rule-20-safe:
// both half-slots written out explicitly, so every b1v/w2f index is a
// compile-time literal). Per slot: [logits of PREVIOUS half from ping-pong
// eh LDS -- its writes were drained by the previous barrier, so the read is
// latency-free] [stage next W1 half via async glds] [ehGEMM] [eh write]
// [barrier]. W1 dbuf + W2/b1 direct-from-L2. LDS ~71.6 KB -> 2 blocks/CU.
// ---------------------------------------------------------------------------
__launch_bounds__(256, 2)
__global__ void expert_kernel(const float* __restrict__ zpart,  // [2][32768][64]
                              const float* __restrict__ z_b,
                              const float* __restrict__ mu,
                              const unsigned short* __restrict__ W1t,  // [16][256][64]
                              const float* __restrict__ b1,
                              const unsigned short* __restrict__ W2t,  // [16][16][256]
                              const float* __restrict__ b2,
                              float* __restrict__ out) {
    __shared__ __align__(16) union SU {
        struct {
            float zs[64][68];    // padded: row stride 68 dwords == 4 mod 32
            float mus[16][68];
            float rn[64];
            float mun[16];
        } a;                                         // ~22.1 KB
        struct {
            unsigned short w1s[2][128][64];          // 32 KB double-buffered W1 halves
            unsigned short ehs[4][2][16][136];       // per-wave ping-pong eh, 34.8 KB
        } b;
    } su;
    __shared__ float qs[64][16];                     // 4 KB

    const int t = threadIdx.x;
    const int lane = t & 63;
    const int w = t >> 6;
    const int g = lane >> 4;
    const int l15 = lane & 15;
    const int l7 = l15 & 7;
    const int r0 = blockIdx.x * 64;

    // P0: z = zpart0 + zpart1 + z_b (64x64 f32) + mu into padded LDS
    {
        const float* zp0 = zpart;
        const float* zp1 = zpart + (size_t)N_ROWS * NZ;
#pragma unroll
        for (int it = 0; it < 4; ++it) {
            int idx = it * 256 + t;              // 1024 float4-slots
            int r = idx >> 4, c = (idx & 15) * 4;
            float4 a = *(const float4*)(zp0 + (size_t)(r0 + r) * NZ + c);
            float4 b = *(const float4*)(zp1 + (size_t)(r0 + r) * NZ + c);
            float4 zb = *(const float4*)(z_b + c);
            float4 s;
            s.x = a.x + b.x + zb.x; s.y = a.y + b.y + zb.y;
            s.z = a.z + b.z + zb.z; s.w = a.w + b.w + zb.w;
            *(float4*)&su.a.zs[r][c] = s;
        }
        int r = t >> 4, c = (t & 15) * 4;        // 256 float4-slots for mu
        *(float4*)&su.a.mus[r][c] = *(const float4*)(mu + (size_t)r * NZ + c);
    }
    __syncthreads();

    // P1a: row norms |z|^2 (t<64) and |mu|^2 (t in 64..79)
    if (t < 64) {
        float s = 0.f;
#pragma unroll
        for (int dq = 0; dq < 16; ++dq) {
            float4 v = *(const float4*)&su.a.zs[t][dq * 4];
            s += v.x * v.x + v.y * v.y + v.z * v.z + v.w * v.w;
        }
        su.a.rn[t] = s;
    } else if (t < 80) {
        int k = t - 64;
        float s = 0.f;
#pragma unroll
        for (int dq = 0; dq < 16; ++dq) {
            float4 v = *(const float4*)&su.a.mus[k][dq * 4];
            s += v.x * v.x + v.y * v.y + v.z * v.z + v.w * v.w;
        }
        su.a.mun[k] = s;
    }
    __syncthreads();

    // P1b: z fragments (kept for expert GEMMs) + dist via MFMA -> raw q
    bf16x8 az[2];
#pragma unroll
    for (int ks = 0; ks < 2; ++ks) {
        int row = w * 16 + l15;
        int ko = ks * 32 + g * 8;
        float4 lo = *(const float4*)&su.a.zs[row][ko];
        float4 hi = *(const float4*)&su.a.zs[row][ko + 4];
        u16x8 tmp;
        tmp[0] = f2bf(lo.x); tmp[1] = f2bf(lo.y); tmp[2] = f2bf(lo.z); tmp[3] = f2bf(lo.w);
        tmp[4] = f2bf(hi.x); tmp[5] = f2bf(hi.y); tmp[6] = f2bf(hi.z); tmp[7] = f2bf(hi.w);
        az[ks] = __builtin_bit_cast(bf16x8, tmp);
    }
    {
        bf16x8 bmu[2];
#pragma unroll
        for (int ks = 0; ks < 2; ++ks) {
            int ko = ks * 32 + g * 8;
            float4 lo = *(const float4*)&su.a.mus[l15][ko];
            float4 hi = *(const float4*)&su.a.mus[l15][ko + 4];
            u16x8 tmp;
            tmp[0] = f2bf(lo.x); tmp[1] = f2bf(lo.y); tmp[2] = f2bf(lo.z); tmp[3] = f2bf(lo.w);
            tmp[4] = f2bf(hi.x); tmp[5] = f2bf(hi.y); tmp[6] = f2bf(hi.z); tmp[7] = f2bf(hi.w);
            bmu[ks] = __builtin_bit_cast(bf16x8, tmp);
        }
        f32x4 dacc = f32x4{0.f, 0.f, 0.f, 0.f};
#pragma unroll
        for (int ks = 0; ks < 2; ++ks)
            dacc = __builtin_amdgcn_mfma_f32_16x16x32_bf16(az[ks], bmu[ks], dacc, 0, 0, 0);
#pragma unroll
        for (int r = 0; r < 4; ++r) {
            int rl = w * 16 + g * 4 + r;
            float dist = su.a.rn[rl] - 2.f * dacc[r] + su.a.mun[l15];
            qs[rl][l15] = 1.f / (1.f + dist);
        }
    }
    __syncthreads();

    // P1c: normalize q per row
    if (t < 64) {
        float s = 0.f;
#pragma unroll
        for (int k = 0; k < KE; ++k) s += qs[t][k];
        float inv = 1.f / s;
#pragma unroll
        for (int k = 0; k < KE; ++k) qs[t][k] *= inv;
    }
    __syncthreads();   // qs final, zs dead -> w1s/ehs may alias su.a

    // P3: expert loop, delayed-logits. All register-array indices static.
    const int srow = lane >> 3;                       // 0..7 (row within chunk)
    const int scol = SWZ((lane & 7) * 8, srow);       // pre-swizzled source col

    // prologue: stage (e=0, half0) into w1s[0]
#pragma unroll
    for (int it = 0; it < 4; ++it) {
        const int chunk = it * 4 + w;                 // 16 chunks of 8 rows
        gload_lds16(&su.b.w1s[0][chunk * 8][0],
                    W1t + (size_t)(chunk * 8 + srow) * NZ + scol);
    }
    __syncthreads();                                  // half0 staged

    float pacc[4] = {0.f, 0.f, 0.f, 0.f};
    f32x4 la = f32x4{0.f, 0.f, 0.f, 0.f};
    bf16x8 w2f[8];
    float b1v[2][8];
    unsigned short* eh0 = &su.b.ehs[w][0][0][0];      // ping (written even slots)
    unsigned short* eh1 = &su.b.ehs[w][1][0][0];      // pong (written odd slots)

    for (int e = 0; e < KE; ++e) {
        // =========== slot 2e (half 0) ===========
        // 1) logits for (e-1, half1): reads eh1 (drained by prev barrier),
        //    uses OLD w2f[4..7]; then combine expert e-1.
        if (e > 0) {
#pragma unroll
            for (int ks2 = 0; ks2 < 4; ++ks2) {
                bf16x8 ef = *(const bf16x8*)&eh1[l15 * 136 + ks2 * 32 + g * 8];
                la = __builtin_amdgcn_mfma_f32_16x16x32_bf16(ef, w2f[4 + ks2], la, 0, 0, 0);
            }
            float b2v = (l15 < NC) ? b2[(e - 1) * NC + l15] : 0.f;
#pragma unroll
            for (int r = 0; r < 4; ++r) {
                int rl = w * 16 + g * 4 + r;
                pacc[r] += qs[rl][e - 1] * (la[r] + b2v);
            }
            la = f32x4{0.f, 0.f, 0.f, 0.f};
        }
        // 2) stage (e, half1) into w1s[1] (drains at this slot's barrier)
        {
            const unsigned short* src =
                W1t + (size_t)e * (HEXP * NZ) + (size_t)(128 + srow) * NZ + scol;
#pragma unroll
            for (int it = 0; it < 4; ++it) {
                const int chunk = it * 4 + w;
                gload_lds16(&su.b.w1s[1][chunk * 8][0], src + (size_t)chunk * 8 * NZ);
            }
        }
        // 3) new w2f/b1 for expert e (consumed slots 2e+1 / 2e+2: full-slot cover)
        {
            const unsigned short* w2e = W2t + e * (16 * HEXP);
#pragma unroll
            for (int hh = 0; hh < 8; ++hh)
                w2f[hh] = *(const bf16x8*)(w2e + (size_t)l15 * HEXP + hh * 32 + g * 8);
#pragma unroll
            for (int j = 0; j < 8; ++j) {
                b1v[0][j] = b1[e * HEXP + j * 16 + l15];
                b1v[1][j] = b1[e * HEXP + 128 + j * 16 + l15];
            }
        }
        // 4) ehGEMM half0 from w1s[0]; bias+relu -> eh0
        {
            f32x4 ea[8];
#pragma unroll
            for (int j = 0; j < 8; ++j) ea[j] = f32x4{0.f, 0.f, 0.f, 0.f};
#pragma unroll
            for (int ks = 0; ks < 2; ++ks) {
                const int sko = SWZ(ks * 32 + g * 8, l7);
#pragma unroll
                for (int j = 0; j < 8; ++j) {
                    bf16x8 bw = *(const bf16x8*)&su.b.w1s[0][j * 16 + l15][sko];
                    ea[j] = __builtin_amdgcn_mfma_f32_16x16x32_bf16(az[ks], bw, ea[j], 0, 0, 0);
                }
            }
#pragma unroll
            for (int j = 0; j < 8; ++j) {
#pragma unroll
                for (int r = 0; r < 4; ++r) {
                    float v = ea[j][r] + b1v[0][j];
                    v = v > 0.f ? v : 0.f;
                    eh0[(g * 4 + r) * 136 + j * 16 + l15] = f2bf(v);
                }
            }
        }
        __syncthreads();

        // =========== slot 2e+1 (half 1) ===========
        // 1) logits for (e, half0): reads eh0, uses w2f[0..3] (no combine yet)
#pragma unroll
        for (int ks2 = 0; ks2 < 4; ++ks2) {
            bf16x8 ef = *(const bf16x8*)&eh0[l15 * 136 + ks2 * 32 + g * 8];
            la = __builtin_amdgcn_mfma_f32_16x16x32_bf16(ef, w2f[ks2], la, 0, 0, 0);
        }
        // 2) stage (e+1, half0) into w1s[0] (last read before prev barrier)
        if (e + 1 < KE) {
            const unsigned short* src =
                W1t + (size_t)(e + 1) * (HEXP * NZ) + (size_t)srow * NZ + scol;
#pragma unroll
            for (int it = 0; it < 4; ++it) {
                const int chunk = it * 4 + w;
                gload_lds16(&su.b.w1s[0][chunk * 8][0], src + (size_t)chunk * 8 * NZ);
            }
        }
        // 3) ehGEMM half1 from w1s[1]; bias+relu -> eh1
        {
            f32x4 ea[8];
#pragma unroll
            for (int j = 0; j < 8; ++j) ea[j] = f32x4{0.f, 0.f, 0.f, 0.f};
#pragma unroll
            for (int ks = 0; ks < 2; ++ks) {
                const int sko = SWZ(ks * 32 + g * 8, l7);
#pragma unroll
                for (int j = 0; j < 8; ++j) {
                    bf16x8 bw = *(const bf16x8*)&su.b.w1s[1][j * 16 + l15][sko];
                    ea[j] = __builtin_amdgcn_mfma_f32_16x16x32_bf16(az[ks], bw, ea[j], 0, 0, 0);
                }
            }
#pragma unroll
            for (int j = 0; j < 8; ++j) {
#pragma unroll
                for (int r = 0; r < 4; ++r) {
                    float v = ea[j][r] + b1v[1][j];
                    v = v > 0.f ? v : 0.f;
                    eh1[(g * 4 + r) * 136 + j * 16 + l15] = f2bf(v);
                }
            }
        }
        __syncthreads();
    }

    // epilogue: logits (KE-1, half1) + combine expert KE-1
    {
#pragma unroll
        for (int ks2 = 0; ks2 < 4; ++ks2) {
            bf16x8 ef = *(const bf16x8*)&eh1[l15 * 136 + ks2 * 32 + g * 8];
            la = __builtin_amdgcn_mfma_f32_16x16x32_bf16(ef, w2f[4 + ks2], la, 0, 0, 0);
        }
        float b2v = (l15 < NC) ? b2[(KE - 1) * NC + l15] : 0.f;
#pragma unroll
        for (int r = 0; r < 4; ++r) {
            int rl = w * 16 + g * 4 + r;
            pacc[r] += qs[rl][KE - 1] * (la[r] + b2v);
        }
    }

    // P4: store preds
    if (l15 < NC) {
#pragma unroll
        for (int r = 0; r < 4; ++r) {
            int row = r0 + w * 16 + g * 4 + r;
            out[(size_t)row * NC + l15] = pacc[r];
        }
    }
}

// ---------------------------------------------------------------------------
extern "C" void kernel_launch(void* const* d_in, const int* in_sizes, int n_in,
                              void* d_out, int out_size, void* d_ws, size_t ws_size,
                              hipStream_t stream) {
    const float* X     = (const float*)d_in[0];
    const float* enc_W = (const float*)d_in[1];
    const float* enc_b = (const float*)d_in[2];
    const float* z_W   = (const float*)d_in[3];
    const float* z_b   = (const float*)d_in[4];
    const float* mu    = (const float*)d_in[5];
    const float* W1    = (const float*)d_in[6];
    const float* b1    = (const float*)d_in[7];
    const float* W2    = (const float*)d_in[8];
    const float* b2    = (const float*)d_in[9];
    float* out = (float*)d_out;

    // workspace layout (~18.5 MB)
    char* ws = (char*)d_ws;
    float*          zpart  = (float*)(ws);                       // 16,777,216 B
    unsigned short* enc_Wt = (unsigned short*)(ws + 16777216);   //  1,048,576 B
    unsigned short* z_Wt   = (unsigned short*)(ws + 17825792);   //     65,536 B
    unsigned short* W1t    = (unsigned short*)(ws + 17891328);   //    524,288 B
    unsigned short* W2t    = (unsigned short*)(ws + 18415616);   //    131,072 B

    prep_weights<<<dim3(216), dim3(256), 0, stream>>>(enc_W, z_W, W1, W2,
                                                      enc_Wt, z_Wt, W1t, W2t);
    gemm1<<<dim3(512), dim3(256), 0, stream>>>(X, enc_Wt, enc_b, z_Wt, zpart);
    expert_kernel<<<dim3(512), dim3(256), 0, stream>>>(zpart, z_b, mu, W1t, b1, W2t, b2, out);
}